// Round 1
// baseline (1359.017 us; speedup 1.0000x reference)
//
#include <hip/hip_runtime.h>
#include <math.h>

#define BB 4
#define CCH 256
#define NSP 2304   // 48*48
#define NHEAD 8
#define DH 32

// ---------------- K1: conv3x3 SAME + bias + BN + ReLU -> x1 [b][c][n] -------
__global__ __launch_bounds__(256) void k_conv(const float* __restrict__ Vx,
    const float* __restrict__ cw, const float* __restrict__ cb,
    const float* __restrict__ g, const float* __restrict__ be,
    const float* __restrict__ mu, const float* __restrict__ va,
    float* __restrict__ x1)
{
  __shared__ float tile[2500];          // 50x50 padded input plane
  const int tid = threadIdx.x;
  const int bid = blockIdx.x;           // 4 b * 64 co-groups
  const int b   = bid >> 6;
  const int co0 = (bid & 63) << 2;      // 4 c_out per block

  int ys[3], xs[3];
#pragma unroll
  for (int i = 0; i < 3; ++i) { int s = i*256 + tid; ys[i] = s >> 4; xs[i] = (s & 15)*3; }

  float acc[4][9];
#pragma unroll
  for (int j = 0; j < 4; ++j)
#pragma unroll
    for (int t = 0; t < 9; ++t) acc[j][t] = 0.f;

  const float* inb = Vx + b*CCH*NSP;
  for (int ci = 0; ci < CCH; ++ci) {
    __syncthreads();
    const float* plane = inb + ci*NSP;
#pragma unroll
    for (int l = 0; l < 10; ++l) {
      int idx = l*256 + tid;
      if (idx < 2500) {
        int r = idx / 50, c = idx - r*50;
        int gy = r - 1, gx = c - 1;
        float v = 0.f;
        if ((unsigned)gy < 48u && (unsigned)gx < 48u) v = plane[gy*48 + gx];
        tile[idx] = v;
      }
    }
    __syncthreads();

    float wt[4][9];
#pragma unroll
    for (int j = 0; j < 4; ++j) {
      const float* wp = cw + ((co0 + j)*CCH + ci)*9;
#pragma unroll
      for (int t = 0; t < 9; ++t) wt[j][t] = wp[t];
    }

#pragma unroll
    for (int i = 0; i < 3; ++i) {
      float win[15];
      const int base = ys[i]*50 + xs[i];
#pragma unroll
      for (int dy = 0; dy < 3; ++dy)
#pragma unroll
        for (int dx = 0; dx < 5; ++dx) win[dy*5+dx] = tile[base + dy*50 + dx];
#pragma unroll
      for (int k = 0; k < 3; ++k)
#pragma unroll
        for (int j = 0; j < 4; ++j) {
          float s = acc[j][i*3+k];
#pragma unroll
          for (int dy = 0; dy < 3; ++dy)
#pragma unroll
            for (int dx = 0; dx < 3; ++dx)
              s = fmaf(wt[j][dy*3+dx], win[dy*5 + k + dx], s);
          acc[j][i*3+k] = s;
        }
    }
  }

#pragma unroll
  for (int j = 0; j < 4; ++j) {
    const int co = co0 + j;
    const float inv = g[co] * rsqrtf(va[co] + 1e-5f);
    const float off = (cb[co] - mu[co]) * inv + be[co];
    float* op = x1 + (b*CCH + co)*NSP;
#pragma unroll
    for (int i = 0; i < 3; ++i)
#pragma unroll
      for (int k = 0; k < 3; ++k) {
        float v = fmaxf(fmaf(acc[j][i*3+k], inv, off), 0.f);
        op[ys[i]*48 + xs[i] + k] = v;
      }
  }
}

// ---------------- K2/K4: 16xK GEMM; MODE 0 -> qkv transposed store ----------
template<int MODE>
__global__ __launch_bounds__(128) void k_gemm(const float* __restrict__ X,
    const float* __restrict__ Wm, const float* __restrict__ bias,
    float* __restrict__ Y, int OT)
{
  __shared__ float wl[16][17];
  __shared__ float xl[16][256];
  const int tid = threadIdx.x;
  int bid = blockIdx.x;
  const int nt = bid % 9; bid /= 9;
  const int ot = bid % OT; const int b = bid / OT;
  const int o0 = ot*16, n0 = nt*256;

  float a0[16], a1[16];
#pragma unroll
  for (int i = 0; i < 16; ++i) { a0[i] = 0.f; a1[i] = 0.f; }

  const float* xb = X + b*CCH*NSP + n0;
  for (int c0 = 0; c0 < CCH; c0 += 16) {
    __syncthreads();
#pragma unroll
    for (int t = 0; t < 2; ++t) {
      int idx = t*128 + tid;
      wl[idx >> 4][idx & 15] = Wm[(o0 + (idx >> 4))*CCH + c0 + (idx & 15)];
    }
#pragma unroll
    for (int r = 0; r < 16; ++r) {
      xl[r][tid]     = xb[(c0 + r)*NSP + tid];
      xl[r][tid+128] = xb[(c0 + r)*NSP + tid + 128];
    }
    __syncthreads();
#pragma unroll
    for (int cc = 0; cc < 16; ++cc) {
      const float xv0 = xl[cc][tid];
      const float xv1 = xl[cc][tid+128];
#pragma unroll
      for (int oo = 0; oo < 16; ++oo) {
        const float w = wl[oo][cc];
        a0[oo] = fmaf(w, xv0, a0[oo]);
        a1[oo] = fmaf(w, xv1, a1[oo]);
      }
    }
  }

  if (MODE == 0) {
    // o = head*96 + comp*32 + e ; 16-tile stays within one comp
    const int head = o0 / 96, rem = o0 % 96;
    const int comp = rem >> 5, e0 = rem & 31;
    float* yb = Y + (size_t)((b*NHEAD + head)*3 + comp)*NSP*DH + e0;
    float* y0 = yb + (size_t)(n0 + tid)*DH;
    float* y1 = yb + (size_t)(n0 + tid + 128)*DH;
#pragma unroll
    for (int oo = 0; oo < 16; ++oo) {
      const float bv = bias[o0 + oo];
      y0[oo] = a0[oo] + bv;
      y1[oo] = a1[oo] + bv;
    }
  } else {
    float* yb = Y + (size_t)b*CCH*NSP + n0 + tid;
#pragma unroll
    for (int oo = 0; oo < 16; ++oo) {
      const float bv = bias[o0 + oo];
      yb[(size_t)(o0+oo)*NSP]       = a0[oo] + bv;
      yb[(size_t)(o0+oo)*NSP + 128] = a1[oo] + bv;
    }
  }
}

// ---------------- K3: attention (thread = one query; split-K additive) ------
// scores are tiny by construction (|s| <~ 1) -> exp without max-subtract is
// exact after normalization, making split-K partials purely additive.
template<int FINAL>
__global__ __launch_bounds__(256) void k_attn(const float* __restrict__ qkv,
    float* __restrict__ x2, float* __restrict__ pacc, float* __restrict__ psum,
    int KS, int klen)
{
  const int tid = threadIdx.x;
  int bid = blockIdx.x;
  const int ks = bid % KS; bid /= KS;
  const int nt = bid % 9;  bid /= 9;
  const int bh = bid;                       // b*8 + head
  const int n  = nt*256 + tid;

  const float* base = qkv + (size_t)bh*3*NSP*DH;
  const float* qp = base + (size_t)n*DH;
  const float* kb = base + (size_t)NSP*DH;
  const float* vb = base + (size_t)2*NSP*DH;
  const float sc = 0.17677669529663687f;    // 1/sqrt(32)

  float q[32];
#pragma unroll
  for (int e = 0; e < 32; e += 4) {
    float4 t = *(const float4*)(qp + e);
    q[e] = t.x*sc; q[e+1] = t.y*sc; q[e+2] = t.z*sc; q[e+3] = t.w*sc;
  }
  float acc[32];
#pragma unroll
  for (int e = 0; e < 32; ++e) acc[e] = 0.f;
  float sm = 0.f;

  const int m0 = ks*klen;
  for (int m = m0; m < m0 + klen; ++m) {
    const float* kc = kb + (size_t)m*DH;    // wave-uniform -> scalar loads
    float s0 = 0.f, s1 = 0.f, s2 = 0.f, s3 = 0.f;
#pragma unroll
    for (int e = 0; e < 32; e += 4) {
      s0 = fmaf(kc[e],   q[e],   s0);
      s1 = fmaf(kc[e+1], q[e+1], s1);
      s2 = fmaf(kc[e+2], q[e+2], s2);
      s3 = fmaf(kc[e+3], q[e+3], s3);
    }
    const float p = __expf((s0 + s1) + (s2 + s3));
    sm += p;
    const float* vc = vb + (size_t)m*DH;    // wave-uniform -> scalar loads
#pragma unroll
    for (int e = 0; e < 32; ++e) acc[e] = fmaf(p, vc[e], acc[e]);
  }

  if (FINAL) {
    const float r = 1.f / sm;
    float* op = x2 + (size_t)bh*DH*NSP + n;
#pragma unroll
    for (int e = 0; e < 32; ++e) op[(size_t)e*NSP] = acc[e]*r;
  } else {
    float* pa = pacc + ((size_t)(bh*KS + ks)*NSP + n)*DH;
#pragma unroll
    for (int e = 0; e < 32; e += 4) {
      float4 t; t.x = acc[e]; t.y = acc[e+1]; t.z = acc[e+2]; t.w = acc[e+3];
      *(float4*)(pa + e) = t;
    }
    psum[(size_t)(bh*KS + ks)*NSP + n] = sm;
  }
}

__global__ __launch_bounds__(256) void k_combine(const float* __restrict__ pacc,
    const float* __restrict__ psum, float* __restrict__ x2, int KS)
{
  const int gid = blockIdx.x*256 + threadIdx.x;   // 73728 queries
  const int n  = gid % NSP;
  const int bh = gid / NSP;
  float acc[32];
#pragma unroll
  for (int e = 0; e < 32; ++e) acc[e] = 0.f;
  float sm = 0.f;
  for (int ks = 0; ks < KS; ++ks) {
    const float* pa = pacc + ((size_t)(bh*KS + ks)*NSP + n)*DH;
#pragma unroll
    for (int e = 0; e < 32; e += 4) {
      float4 t = *(const float4*)(pa + e);
      acc[e] += t.x; acc[e+1] += t.y; acc[e+2] += t.z; acc[e+3] += t.w;
    }
    sm += psum[(size_t)(bh*KS + ks)*NSP + n];
  }
  const float r = 1.f / sm;
  float* op = x2 + (size_t)bh*DH*NSP + n;
#pragma unroll
  for (int e = 0; e < 32; ++e) op[(size_t)e*NSP] = acc[e]*r;
}

// ---------------------------------------------------------------------------
extern "C" void kernel_launch(void* const* d_in, const int* in_sizes, int n_in,
                              void* d_out, int out_size, void* d_ws, size_t ws_size,
                              hipStream_t stream)
{
  const float* Vx = (const float*)d_in[0];
  const float* cw = (const float*)d_in[1];
  const float* cb = (const float*)d_in[2];
  const float* g  = (const float*)d_in[3];
  const float* be = (const float*)d_in[4];
  const float* mu = (const float*)d_in[5];
  const float* va = (const float*)d_in[6];
  const float* qw = (const float*)d_in[7];
  const float* qb = (const float*)d_in[8];
  const float* pw = (const float*)d_in[9];
  const float* pb = (const float*)d_in[10];
  float* out = (float*)d_out;
  float* ws  = (float*)d_ws;

  float* x1   = ws;                        // 2359296 floats (reused as x2)
  float* qkvt = ws + 2359296;              // 7077888 floats
  float* pacc = ws + 2359296 + 7077888;

  const size_t baseB = (size_t)(2359296 + 7077888)*4;
  const size_t perKS = (size_t)73728*33*4; // pacc+psum per split = 9732096 B
  int KS = 1;
  if      (ws_size >= baseB + 4*perKS) KS = 4;
  else if (ws_size >= baseB + 2*perKS) KS = 2;
  float* psum = pacc + (size_t)73728*KS*32;

  k_conv<<<256, 256, 0, stream>>>(Vx, cw, cb, g, be, mu, va, x1);
  k_gemm<0><<<4*48*9, 128, 0, stream>>>(x1, qw, qb, qkvt, 48);

  float* x2 = x1;   // x1 dead after QKV
  if (KS == 1) {
    k_attn<1><<<4*8*9, 256, 0, stream>>>(qkvt, x2, nullptr, nullptr, 1, NSP);
  } else {
    k_attn<0><<<4*8*9*KS, 256, 0, stream>>>(qkvt, x2, pacc, psum, KS, NSP/KS);
    k_combine<<<288, 256, 0, stream>>>(pacc, psum, x2, KS);
  }
  k_gemm<1><<<4*16*9, 128, 0, stream>>>(x2, pw, pb, out, 16);
}

// Round 2
// 749.293 us; speedup vs baseline: 1.8137x; 1.8137x over previous
//
#include <hip/hip_runtime.h>
#include <math.h>

#define BB 4
#define CCH 256
#define NSP 2304   // 48*48
#define NHEAD 8
#define DH 32

// ---------------- K1: conv3x3 SAME + bias + BN + ReLU -> x1 [b][c][n] -------
// Tile: 8 co x 8 rows x 48 cols per block; ci staged in LDS chunks of 16.
// grid = 4b * 32 co-tiles * 6 row-tiles = 768 blocks (3/CU, 12 waves/CU).
#define CP 53            // padded LDS row stride (bank spread: 21*r + 6*c mod 32)
#define CISTRIDE 530     // 10 rows * 53
#define CICHUNK 16

__global__ __launch_bounds__(256) void k_conv(const float* __restrict__ Vx,
    const float* __restrict__ cw, const float* __restrict__ cb,
    const float* __restrict__ g, const float* __restrict__ be,
    const float* __restrict__ mu, const float* __restrict__ va,
    float* __restrict__ x1)
{
  __shared__ float tile[CICHUNK * CISTRIDE];   // 33920 B
  const int tid = threadIdx.x;
  int bid = blockIdx.x;
  const int rt  = bid % 6;  bid /= 6;
  const int cot = bid % 32; const int b = bid / 32;
  const int co0  = cot * 8;
  const int row0 = rt * 8;

  const int w  = __builtin_amdgcn_readfirstlane(tid >> 6);  // wave id (uniform)
  const int l  = tid & 63;
  const int lrow = l >> 3;          // 0..7 output row within tile
  const int cs   = (l & 7) * 6;     // strip start col (6 wide)

  const float* inb = Vx + (size_t)b * CCH * NSP;
  const int coA = co0 + 2 * w;      // this wave's two output channels

  float acc[2][6];
#pragma unroll
  for (int j = 0; j < 2; ++j)
#pragma unroll
    for (int s = 0; s < 6; ++s) acc[j][s] = 0.f;

  for (int c0 = 0; c0 < CCH; c0 += CICHUNK) {
    __syncthreads();
    // ---- stage 16 planes: rows gy=row0-1..row0+8, cols gx=-1..48 (50 wide)
#pragma unroll
    for (int it = 0; it < 32; ++it) {
      int idx = it * 256 + tid;
      if (idx < CICHUNK * 500) {
        int ci  = idx / 500;
        int rem = idx - ci * 500;
        int r   = rem / 50;
        int c   = rem - r * 50;
        int gy = row0 + r - 1;
        int gx = c - 1;
        float v = 0.f;
        if ((unsigned)gy < 48u && (unsigned)gx < 48u)
          v = inb[(size_t)(c0 + ci) * NSP + gy * 48 + gx];
        tile[ci * CISTRIDE + r * CP + c] = v;
      }
    }
    __syncthreads();

    // ---- compute 16 ci
#pragma unroll 4
    for (int cc = 0; cc < CICHUNK; ++cc) {
      // weights: wave-uniform address -> scalar loads
      const float* wp0 = cw + ((size_t)(coA    ) * CCH + c0 + cc) * 9;
      const float* wp1 = cw + ((size_t)(coA + 1) * CCH + c0 + cc) * 9;
      float wt0[9], wt1[9];
#pragma unroll
      for (int t = 0; t < 9; ++t) { wt0[t] = wp0[t]; wt1[t] = wp1[t]; }

      float win[3][8];
      const int basea = cc * CISTRIDE + lrow * CP + cs;
#pragma unroll
      for (int dy = 0; dy < 3; ++dy)
#pragma unroll
        for (int dx = 0; dx < 8; ++dx)
          win[dy][dx] = tile[basea + dy * CP + dx];

#pragma unroll
      for (int s = 0; s < 6; ++s)
#pragma unroll
        for (int dy = 0; dy < 3; ++dy)
#pragma unroll
          for (int dx = 0; dx < 3; ++dx) {
            const float xv = win[dy][s + dx];
            acc[0][s] = fmaf(wt0[dy*3+dx], xv, acc[0][s]);
            acc[1][s] = fmaf(wt1[dy*3+dx], xv, acc[1][s]);
          }
    }
  }

  // ---- epilogue: bias + BN + ReLU, write 2 co x 6 cols
#pragma unroll
  for (int j = 0; j < 2; ++j) {
    const int co = coA + j;
    const float inv = g[co] * rsqrtf(va[co] + 1e-5f);
    const float off = (cb[co] - mu[co]) * inv + be[co];
    float* op = x1 + ((size_t)(b * CCH + co)) * NSP + (row0 + lrow) * 48 + cs;
#pragma unroll
    for (int s = 0; s < 6; ++s)
      op[s] = fmaxf(fmaf(acc[j][s], inv, off), 0.f);
  }
}

// ---------------- K2/K4: 16xK GEMM; MODE 0 -> qkv transposed store ----------
template<int MODE>
__global__ __launch_bounds__(128) void k_gemm(const float* __restrict__ X,
    const float* __restrict__ Wm, const float* __restrict__ bias,
    float* __restrict__ Y, int OT)
{
  __shared__ float wl[16][17];
  __shared__ float xl[16][256];
  const int tid = threadIdx.x;
  int bid = blockIdx.x;
  const int nt = bid % 9; bid /= 9;
  const int ot = bid % OT; const int b = bid / OT;
  const int o0 = ot*16, n0 = nt*256;

  float a0[16], a1[16];
#pragma unroll
  for (int i = 0; i < 16; ++i) { a0[i] = 0.f; a1[i] = 0.f; }

  const float* xb = X + b*CCH*NSP + n0;
  for (int c0 = 0; c0 < CCH; c0 += 16) {
    __syncthreads();
#pragma unroll
    for (int t = 0; t < 2; ++t) {
      int idx = t*128 + tid;
      wl[idx >> 4][idx & 15] = Wm[(o0 + (idx >> 4))*CCH + c0 + (idx & 15)];
    }
#pragma unroll
    for (int r = 0; r < 16; ++r) {
      xl[r][tid]     = xb[(c0 + r)*NSP + tid];
      xl[r][tid+128] = xb[(c0 + r)*NSP + tid + 128];
    }
    __syncthreads();
#pragma unroll
    for (int cc = 0; cc < 16; ++cc) {
      const float xv0 = xl[cc][tid];
      const float xv1 = xl[cc][tid+128];
#pragma unroll
      for (int oo = 0; oo < 16; ++oo) {
        const float w = wl[oo][cc];
        a0[oo] = fmaf(w, xv0, a0[oo]);
        a1[oo] = fmaf(w, xv1, a1[oo]);
      }
    }
  }

  if (MODE == 0) {
    // o = head*96 + comp*32 + e ; 16-tile stays within one comp
    const int head = o0 / 96, rem = o0 % 96;
    const int comp = rem >> 5, e0 = rem & 31;
    float* yb = Y + (size_t)((b*NHEAD + head)*3 + comp)*NSP*DH + e0;
    float* y0 = yb + (size_t)(n0 + tid)*DH;
    float* y1 = yb + (size_t)(n0 + tid + 128)*DH;
#pragma unroll
    for (int oo = 0; oo < 16; ++oo) {
      const float bv = bias[o0 + oo];
      y0[oo] = a0[oo] + bv;
      y1[oo] = a1[oo] + bv;
    }
  } else {
    float* yb = Y + (size_t)b*CCH*NSP + n0 + tid;
#pragma unroll
    for (int oo = 0; oo < 16; ++oo) {
      const float bv = bias[o0 + oo];
      yb[(size_t)(o0+oo)*NSP]       = a0[oo] + bv;
      yb[(size_t)(o0+oo)*NSP + 128] = a1[oo] + bv;
    }
  }
}

// ---------------- K3: attention (thread = one query; split-K additive) ------
// scores are tiny by construction (|s| <~ 1) -> exp without max-subtract is
// exact after normalization, making split-K partials purely additive.
template<int FINAL>
__global__ __launch_bounds__(256) void k_attn(const float* __restrict__ qkv,
    float* __restrict__ x2, float* __restrict__ pacc, float* __restrict__ psum,
    int KS, int klen)
{
  const int tid = threadIdx.x;
  int bid = blockIdx.x;
  const int ks = bid % KS; bid /= KS;
  const int nt = bid % 9;  bid /= 9;
  const int bh = bid;                       // b*8 + head
  const int n  = nt*256 + tid;

  const float* base = qkv + (size_t)bh*3*NSP*DH;
  const float* qp = base + (size_t)n*DH;
  const float* kb = base + (size_t)NSP*DH;
  const float* vb = base + (size_t)2*NSP*DH;
  const float sc = 0.17677669529663687f;    // 1/sqrt(32)

  float q[32];
#pragma unroll
  for (int e = 0; e < 32; e += 4) {
    float4 t = *(const float4*)(qp + e);
    q[e] = t.x*sc; q[e+1] = t.y*sc; q[e+2] = t.z*sc; q[e+3] = t.w*sc;
  }
  float acc[32];
#pragma unroll
  for (int e = 0; e < 32; ++e) acc[e] = 0.f;
  float sm = 0.f;

  const int m0 = ks*klen;
  for (int m = m0; m < m0 + klen; ++m) {
    const float* kc = kb + (size_t)m*DH;    // wave-uniform -> scalar loads
    float s0 = 0.f, s1 = 0.f, s2 = 0.f, s3 = 0.f;
#pragma unroll
    for (int e = 0; e < 32; e += 4) {
      s0 = fmaf(kc[e],   q[e],   s0);
      s1 = fmaf(kc[e+1], q[e+1], s1);
      s2 = fmaf(kc[e+2], q[e+2], s2);
      s3 = fmaf(kc[e+3], q[e+3], s3);
    }
    const float p = __expf((s0 + s1) + (s2 + s3));
    sm += p;
    const float* vc = vb + (size_t)m*DH;    // wave-uniform -> scalar loads
#pragma unroll
    for (int e = 0; e < 32; ++e) acc[e] = fmaf(p, vc[e], acc[e]);
  }

  if (FINAL) {
    const float r = 1.f / sm;
    float* op = x2 + (size_t)bh*DH*NSP + n;
#pragma unroll
    for (int e = 0; e < 32; ++e) op[(size_t)e*NSP] = acc[e]*r;
  } else {
    float* pa = pacc + ((size_t)(bh*KS + ks)*NSP + n)*DH;
#pragma unroll
    for (int e = 0; e < 32; e += 4) {
      float4 t; t.x = acc[e]; t.y = acc[e+1]; t.z = acc[e+2]; t.w = acc[e+3];
      *(float4*)(pa + e) = t;
    }
    psum[(size_t)(bh*KS + ks)*NSP + n] = sm;
  }
}

__global__ __launch_bounds__(256) void k_combine(const float* __restrict__ pacc,
    const float* __restrict__ psum, float* __restrict__ x2, int KS)
{
  const int gid = blockIdx.x*256 + threadIdx.x;   // 73728 queries
  const int n  = gid % NSP;
  const int bh = gid / NSP;
  float acc[32];
#pragma unroll
  for (int e = 0; e < 32; ++e) acc[e] = 0.f;
  float sm = 0.f;
  for (int ks = 0; ks < KS; ++ks) {
    const float* pa = pacc + ((size_t)(bh*KS + ks)*NSP + n)*DH;
#pragma unroll
    for (int e = 0; e < 32; e += 4) {
      float4 t = *(const float4*)(pa + e);
      acc[e] += t.x; acc[e+1] += t.y; acc[e+2] += t.z; acc[e+3] += t.w;
    }
    sm += psum[(size_t)(bh*KS + ks)*NSP + n];
  }
  const float r = 1.f / sm;
  float* op = x2 + (size_t)bh*DH*NSP + n;
#pragma unroll
  for (int e = 0; e < 32; ++e) op[(size_t)e*NSP] = acc[e]*r;
}

// ---------------------------------------------------------------------------
extern "C" void kernel_launch(void* const* d_in, const int* in_sizes, int n_in,
                              void* d_out, int out_size, void* d_ws, size_t ws_size,
                              hipStream_t stream)
{
  const float* Vx = (const float*)d_in[0];
  const float* cw = (const float*)d_in[1];
  const float* cb = (const float*)d_in[2];
  const float* g  = (const float*)d_in[3];
  const float* be = (const float*)d_in[4];
  const float* mu = (const float*)d_in[5];
  const float* va = (const float*)d_in[6];
  const float* qw = (const float*)d_in[7];
  const float* qb = (const float*)d_in[8];
  const float* pw = (const float*)d_in[9];
  const float* pb = (const float*)d_in[10];
  float* out = (float*)d_out;
  float* ws  = (float*)d_ws;

  float* x1   = ws;                        // 2359296 floats (reused as x2)
  float* qkvt = ws + 2359296;              // 7077888 floats
  float* pacc = ws + 2359296 + 7077888;

  const size_t baseB = (size_t)(2359296 + 7077888)*4;
  const size_t perKS = (size_t)73728*33*4; // pacc+psum per split = 9732096 B
  int KS = 1;
  if      (ws_size >= baseB + 4*perKS) KS = 4;
  else if (ws_size >= baseB + 2*perKS) KS = 2;
  float* psum = pacc + (size_t)73728*KS*32;

  k_conv<<<768, 256, 0, stream>>>(Vx, cw, cb, g, be, mu, va, x1);
  k_gemm<0><<<4*48*9, 128, 0, stream>>>(x1, qw, qb, qkvt, 48);

  float* x2 = x1;   // x1 dead after QKV
  if (KS == 1) {
    k_attn<1><<<4*8*9, 256, 0, stream>>>(qkvt, x2, nullptr, nullptr, 1, NSP);
  } else {
    k_attn<0><<<4*8*9*KS, 256, 0, stream>>>(qkvt, x2, pacc, psum, KS, NSP/KS);
    k_combine<<<288, 256, 0, stream>>>(pacc, psum, x2, KS);
  }
  k_gemm<1><<<4*16*9, 128, 0, stream>>>(x2, pw, pb, out, 16);
}

// Round 3
// 484.362 us; speedup vs baseline: 2.8058x; 1.5470x over previous
//
#include <hip/hip_runtime.h>
#include <math.h>

#define BB 4
#define CCH 256
#define NSP 2304   // 48*48
#define NHEAD 8
#define DH 32

typedef __bf16 bf16x8 __attribute__((ext_vector_type(8)));
typedef float f32x16 __attribute__((ext_vector_type(16)));
typedef unsigned u32x4 __attribute__((ext_vector_type(4)));

// ---------------- K1: conv3x3 SAME + bias + BN + ReLU -> x1 [b][c][n] -------
#define CP 53
#define CISTRIDE 530
#define CICHUNK 16

__global__ __launch_bounds__(256) void k_conv(const float* __restrict__ Vx,
    const float* __restrict__ cw, const float* __restrict__ cb,
    const float* __restrict__ g, const float* __restrict__ be,
    const float* __restrict__ mu, const float* __restrict__ va,
    float* __restrict__ x1)
{
  __shared__ float tile[CICHUNK * CISTRIDE];
  const int tid = threadIdx.x;
  int bid = blockIdx.x;
  const int rt  = bid % 6;  bid /= 6;
  const int cot = bid % 32; const int b = bid / 32;
  const int co0  = cot * 8;
  const int row0 = rt * 8;

  const int w  = __builtin_amdgcn_readfirstlane(tid >> 6);
  const int l  = tid & 63;
  const int lrow = l >> 3;
  const int cs   = (l & 7) * 6;

  const float* inb = Vx + (size_t)b * CCH * NSP;
  const int coA = co0 + 2 * w;

  float acc[2][6];
#pragma unroll
  for (int j = 0; j < 2; ++j)
#pragma unroll
    for (int s = 0; s < 6; ++s) acc[j][s] = 0.f;

  for (int c0 = 0; c0 < CCH; c0 += CICHUNK) {
    __syncthreads();
#pragma unroll
    for (int it = 0; it < 32; ++it) {
      int idx = it * 256 + tid;
      if (idx < CICHUNK * 500) {
        int ci  = idx / 500;
        int rem = idx - ci * 500;
        int r   = rem / 50;
        int c   = rem - r * 50;
        int gy = row0 + r - 1;
        int gx = c - 1;
        float v = 0.f;
        if ((unsigned)gy < 48u && (unsigned)gx < 48u)
          v = inb[(size_t)(c0 + ci) * NSP + gy * 48 + gx];
        tile[ci * CISTRIDE + r * CP + c] = v;
      }
    }
    __syncthreads();

#pragma unroll 4
    for (int cc = 0; cc < CICHUNK; ++cc) {
      const float* wp0 = cw + ((size_t)(coA    ) * CCH + c0 + cc) * 9;
      const float* wp1 = cw + ((size_t)(coA + 1) * CCH + c0 + cc) * 9;
      float wt0[9], wt1[9];
#pragma unroll
      for (int t = 0; t < 9; ++t) { wt0[t] = wp0[t]; wt1[t] = wp1[t]; }

      float win[3][8];
      const int basea = cc * CISTRIDE + lrow * CP + cs;
#pragma unroll
      for (int dy = 0; dy < 3; ++dy)
#pragma unroll
        for (int dx = 0; dx < 8; ++dx)
          win[dy][dx] = tile[basea + dy * CP + dx];

#pragma unroll
      for (int s = 0; s < 6; ++s)
#pragma unroll
        for (int dy = 0; dy < 3; ++dy)
#pragma unroll
          for (int dx = 0; dx < 3; ++dx) {
            const float xv = win[dy][s + dx];
            acc[0][s] = fmaf(wt0[dy*3+dx], xv, acc[0][s]);
            acc[1][s] = fmaf(wt1[dy*3+dx], xv, acc[1][s]);
          }
    }
  }

#pragma unroll
  for (int j = 0; j < 2; ++j) {
    const int co = coA + j;
    const float inv = g[co] * rsqrtf(va[co] + 1e-5f);
    const float off = (cb[co] - mu[co]) * inv + be[co];
    float* op = x1 + ((size_t)(b * CCH + co)) * NSP + (row0 + lrow) * 48 + cs;
#pragma unroll
    for (int s = 0; s < 6; ++s)
      op[s] = fmaxf(fmaf(acc[j][s], inv, off), 0.f);
  }
}

// ---------------- K2/K4: 16xK GEMM; MODE 0 -> qkv transposed store ----------
template<int MODE>
__global__ __launch_bounds__(128) void k_gemm(const float* __restrict__ X,
    const float* __restrict__ Wm, const float* __restrict__ bias,
    float* __restrict__ Y, int OT)
{
  __shared__ float wl[16][17];
  __shared__ float xl[16][256];
  const int tid = threadIdx.x;
  int bid = blockIdx.x;
  const int nt = bid % 9; bid /= 9;
  const int ot = bid % OT; const int b = bid / OT;
  const int o0 = ot*16, n0 = nt*256;

  float a0[16], a1[16];
#pragma unroll
  for (int i = 0; i < 16; ++i) { a0[i] = 0.f; a1[i] = 0.f; }

  const float* xb = X + b*CCH*NSP + n0;
  for (int c0 = 0; c0 < CCH; c0 += 16) {
    __syncthreads();
#pragma unroll
    for (int t = 0; t < 2; ++t) {
      int idx = t*128 + tid;
      wl[idx >> 4][idx & 15] = Wm[(o0 + (idx >> 4))*CCH + c0 + (idx & 15)];
    }
#pragma unroll
    for (int r = 0; r < 16; ++r) {
      xl[r][tid]     = xb[(c0 + r)*NSP + tid];
      xl[r][tid+128] = xb[(c0 + r)*NSP + tid + 128];
    }
    __syncthreads();
#pragma unroll
    for (int cc = 0; cc < 16; ++cc) {
      const float xv0 = xl[cc][tid];
      const float xv1 = xl[cc][tid+128];
#pragma unroll
      for (int oo = 0; oo < 16; ++oo) {
        const float w = wl[oo][cc];
        a0[oo] = fmaf(w, xv0, a0[oo]);
        a1[oo] = fmaf(w, xv1, a1[oo]);
      }
    }
  }

  if (MODE == 0) {
    const int head = o0 / 96, rem = o0 % 96;
    const int comp = rem >> 5, e0 = rem & 31;
    float* yb = Y + (size_t)((b*NHEAD + head)*3 + comp)*NSP*DH + e0;
    float* y0 = yb + (size_t)(n0 + tid)*DH;
    float* y1 = yb + (size_t)(n0 + tid + 128)*DH;
#pragma unroll
    for (int oo = 0; oo < 16; ++oo) {
      const float bv = bias[o0 + oo];
      y0[oo] = a0[oo] + bv;
      y1[oo] = a1[oo] + bv;
    }
  } else {
    float* yb = Y + (size_t)b*CCH*NSP + n0 + tid;
#pragma unroll
    for (int oo = 0; oo < 16; ++oo) {
      const float bv = bias[o0 + oo];
      yb[(size_t)(o0+oo)*NSP]       = a0[oo] + bv;
      yb[(size_t)(o0+oo)*NSP + 128] = a1[oo] + bv;
    }
  }
}

// ---------------- K3: MFMA flash attention -------------------------------
// Swapped QK^T (S^T = K*Q) with 32x32x16 bf16 MFMA; P stays in registers via
// cvt_pk_bf16 + permlane32_swap (T12). K and V^T staged in LDS per 64-key
// step. Scores are tiny (|s|<~1.5) -> exp2 without max-subtract is exact
// after normalization. Rowsum layout (q = lane&31) matches C/D layout.
#define KLS 40   // K_lds row stride (elems): 80B, 16B-aligned frags
#define VLS 72   // Vt_lds row stride (elems): 144B, 16B-aligned frags
#define NSTEP 36 // 2304/64

static __device__ __forceinline__ unsigned cvtpk(float lo, float hi) {
  unsigned r;
  asm("v_cvt_pk_bf16_f32 %0, %1, %2" : "=v"(r) : "v"(lo), "v"(hi));
  return r;
}

__global__ __launch_bounds__(256) void k_attn_mfma(const float* __restrict__ qkvt,
    float* __restrict__ x2)
{
  __shared__ __bf16 K_lds[64 * KLS];
  __shared__ __bf16 Vt_lds[32 * VLS];
  const int tid = threadIdx.x;
  const int bid0 = blockIdx.x;
  // XCD swizzle: 576 = 8 XCDs * 72; each XCD owns 4 consecutive bh
  const int bid = (bid0 & 7) * 72 + (bid0 >> 3);
  const int bh = bid / 18;
  const int qb = bid % 18;
  const int w  = tid >> 6;
  const int l  = tid & 63;
  const int h  = l >> 5;
  const int q  = l & 31;

  const float* qg = qkvt + ((size_t)bh * 3    ) * NSP * DH;
  const float* kg = qkvt + ((size_t)bh * 3 + 1) * NSP * DH;
  const float* vg = qkvt + ((size_t)bh * 3 + 2) * NSP * DH;

  // ---- Q fragments, pre-scaled by log2(e)/sqrt(32)
  const float qsc = 1.4426950408889634f * 0.17677669529663687f;
  const int nq = qb * 128 + w * 32 + q;
  bf16x8 qf0, qf1;
  {
    const float* qp = qg + (size_t)nq * DH + 8 * h;
    float4 t0 = *(const float4*)qp;
    float4 t1 = *(const float4*)(qp + 4);
    qf0[0]=(__bf16)(t0.x*qsc); qf0[1]=(__bf16)(t0.y*qsc); qf0[2]=(__bf16)(t0.z*qsc); qf0[3]=(__bf16)(t0.w*qsc);
    qf0[4]=(__bf16)(t1.x*qsc); qf0[5]=(__bf16)(t1.y*qsc); qf0[6]=(__bf16)(t1.z*qsc); qf0[7]=(__bf16)(t1.w*qsc);
    const float* qp1 = qp + 16;
    float4 t2 = *(const float4*)qp1;
    float4 t3 = *(const float4*)(qp1 + 4);
    qf1[0]=(__bf16)(t2.x*qsc); qf1[1]=(__bf16)(t2.y*qsc); qf1[2]=(__bf16)(t2.z*qsc); qf1[3]=(__bf16)(t2.w*qsc);
    qf1[4]=(__bf16)(t3.x*qsc); qf1[5]=(__bf16)(t3.y*qsc); qf1[6]=(__bf16)(t3.z*qsc); qf1[7]=(__bf16)(t3.w*qsc);
  }

  f32x16 acc0, acc1;
#pragma unroll
  for (int r = 0; r < 16; ++r) { acc0[r] = 0.f; acc1[r] = 0.f; }
  float rs = 0.f;

  // staging coords
  const int krow = tid >> 2, kcol = (tid & 3) * 8;   // K: contiguous loads
  const int vrow = tid & 63, vcol = (tid >> 6) * 8;  // V: per-wave e-chunk

  float4 ka0, ka1, va0, va1;
  {
    const float* kp = kg + (size_t)krow * DH + kcol;
    ka0 = *(const float4*)kp;  ka1 = *(const float4*)(kp + 4);
    const float* vp = vg + (size_t)vrow * DH + vcol;
    va0 = *(const float4*)vp;  va1 = *(const float4*)(vp + 4);
  }

  for (int s = 0; s < NSTEP; ++s) {
    __syncthreads();
    // ---- stage K (1x b128 write) and V^T (8x b16, uniform row per write)
    {
      bf16x8 f;
      f[0]=(__bf16)ka0.x; f[1]=(__bf16)ka0.y; f[2]=(__bf16)ka0.z; f[3]=(__bf16)ka0.w;
      f[4]=(__bf16)ka1.x; f[5]=(__bf16)ka1.y; f[6]=(__bf16)ka1.z; f[7]=(__bf16)ka1.w;
      *(bf16x8*)&K_lds[krow * KLS + kcol] = f;
      Vt_lds[(vcol+0)*VLS + vrow] = (__bf16)va0.x;
      Vt_lds[(vcol+1)*VLS + vrow] = (__bf16)va0.y;
      Vt_lds[(vcol+2)*VLS + vrow] = (__bf16)va0.z;
      Vt_lds[(vcol+3)*VLS + vrow] = (__bf16)va0.w;
      Vt_lds[(vcol+4)*VLS + vrow] = (__bf16)va1.x;
      Vt_lds[(vcol+5)*VLS + vrow] = (__bf16)va1.y;
      Vt_lds[(vcol+6)*VLS + vrow] = (__bf16)va1.z;
      Vt_lds[(vcol+7)*VLS + vrow] = (__bf16)va1.w;
    }
    __syncthreads();
    // ---- prefetch next step (lands during compute)
    if (s + 1 < NSTEP) {
      const int m1 = (s + 1) * 64;
      const float* kp = kg + (size_t)(m1 + krow) * DH + kcol;
      ka0 = *(const float4*)kp;  ka1 = *(const float4*)(kp + 4);
      const float* vp = vg + (size_t)(m1 + vrow) * DH + vcol;
      va0 = *(const float4*)vp;  va1 = *(const float4*)(vp + 4);
    }
    // ---- compute: 2 key-tiles of 32
#pragma unroll
    for (int kt = 0; kt < 2; ++kt) {
      bf16x8 kfr0 = *(bf16x8*)&K_lds[(32*kt + q) * KLS + 8*h];
      bf16x8 kfr1 = *(bf16x8*)&K_lds[(32*kt + q) * KLS + 16 + 8*h];
      f32x16 sv;
#pragma unroll
      for (int r = 0; r < 16; ++r) sv[r] = 0.f;
      sv = __builtin_amdgcn_mfma_f32_32x32x16_bf16(kfr0, qf0, sv, 0, 0, 0);
      sv = __builtin_amdgcn_mfma_f32_32x32x16_bf16(kfr1, qf1, sv, 0, 0, 0);
      float p[16];
#pragma unroll
      for (int r = 0; r < 16; ++r) { p[r] = exp2f(sv[r]); rs += p[r]; }
#pragma unroll
      for (int m = 0; m < 2; ++m) {
        unsigned pk00 = cvtpk(p[8*m+0], p[8*m+1]);
        unsigned pk01 = cvtpk(p[8*m+2], p[8*m+3]);
        unsigned pk10 = cvtpk(p[8*m+4], p[8*m+5]);
        unsigned pk11 = cvtpk(p[8*m+6], p[8*m+7]);
        asm("v_permlane32_swap_b32 %0, %1" : "+v"(pk00), "+v"(pk10));
        asm("v_permlane32_swap_b32 %0, %1" : "+v"(pk01), "+v"(pk11));
        u32x4 pw = {pk00, pk01, pk10, pk11};
        bf16x8 pfr = __builtin_bit_cast(bf16x8, pw);
        const int MT = 2*kt + m;
        bf16x8 vfr = *(bf16x8*)&Vt_lds[q * VLS + 16*MT + 8*h];
        if (MT & 1) acc1 = __builtin_amdgcn_mfma_f32_32x32x16_bf16(vfr, pfr, acc1, 0, 0, 0);
        else        acc0 = __builtin_amdgcn_mfma_f32_32x32x16_bf16(vfr, pfr, acc0, 0, 0, 0);
      }
    }
  }

  // rowsum: each half holds disjoint key rows of column q
  rs += __shfl_xor(rs, 32, 64);
  const float rn = 1.f / rs;

  float* ob = x2 + (size_t)bh * DH * NSP + nq;
#pragma unroll
  for (int r = 0; r < 16; ++r) {
    const int e = (r & 3) + 8 * (r >> 2) + 4 * h;
    ob[(size_t)e * NSP] = (acc0[r] + acc1[r]) * rn;
  }
}

// ---------------------------------------------------------------------------
extern "C" void kernel_launch(void* const* d_in, const int* in_sizes, int n_in,
                              void* d_out, int out_size, void* d_ws, size_t ws_size,
                              hipStream_t stream)
{
  const float* Vx = (const float*)d_in[0];
  const float* cw = (const float*)d_in[1];
  const float* cb = (const float*)d_in[2];
  const float* g  = (const float*)d_in[3];
  const float* be = (const float*)d_in[4];
  const float* mu = (const float*)d_in[5];
  const float* va = (const float*)d_in[6];
  const float* qw = (const float*)d_in[7];
  const float* qb = (const float*)d_in[8];
  const float* pw = (const float*)d_in[9];
  const float* pb = (const float*)d_in[10];
  float* out = (float*)d_out;
  float* ws  = (float*)d_ws;

  float* x1   = ws;                        // 2359296 floats (reused as x2)
  float* qkvt = ws + 2359296;              // 7077888 floats

  k_conv<<<768, 256, 0, stream>>>(Vx, cw, cb, g, be, mu, va, x1);
  k_gemm<0><<<4*48*9, 128, 0, stream>>>(x1, qw, qb, qkvt, 48);

  float* x2 = x1;   // x1 dead after QKV
  k_attn_mfma<<<576, 256, 0, stream>>>(qkvt, x2);

  k_gemm<1><<<4*16*9, 128, 0, stream>>>(x2, pw, pb, out, 16);
}

// Round 4
// 271.675 us; speedup vs baseline: 5.0024x; 1.7829x over previous
//
#include <hip/hip_runtime.h>
#include <math.h>

#define BB 4
#define CCH 256
#define NSP 2304   // 48*48
#define NHEAD 8
#define DH 32

typedef __bf16 bf16x8 __attribute__((ext_vector_type(8)));
typedef float f32x16 __attribute__((ext_vector_type(16)));
typedef unsigned u32x4 __attribute__((ext_vector_type(4)));

// ============ Pre-pass A: Vx fp32 [b][ci][n] -> xt bf16 [b][n][ci] =========
__global__ __launch_bounds__(256) void k_xt(const float* __restrict__ Vx,
    __bf16* __restrict__ xt)
{
  __shared__ __bf16 Lt[64 * 40];
  int bid = blockIdx.x;
  const int nt = bid % 36; bid /= 36;
  const int cit = bid % 8; const int b = bid / 8;
  const int n0 = nt * 64, ci0 = cit * 32;
  const int tid = threadIdx.x;
  {
    const int ci = tid >> 3, ns = (tid & 7) * 8;
    const float* src = Vx + ((size_t)(b * CCH + ci0 + ci)) * NSP + n0 + ns;
    float4 v0 = *(const float4*)src;
    float4 v1 = *(const float4*)(src + 4);
    Lt[(ns+0)*40 + ci] = (__bf16)v0.x;  Lt[(ns+1)*40 + ci] = (__bf16)v0.y;
    Lt[(ns+2)*40 + ci] = (__bf16)v0.z;  Lt[(ns+3)*40 + ci] = (__bf16)v0.w;
    Lt[(ns+4)*40 + ci] = (__bf16)v1.x;  Lt[(ns+5)*40 + ci] = (__bf16)v1.y;
    Lt[(ns+6)*40 + ci] = (__bf16)v1.z;  Lt[(ns+7)*40 + ci] = (__bf16)v1.w;
  }
  __syncthreads();
  {
    const int n = tid >> 2, cip = (tid & 3) * 8;
    bf16x8 r = *(bf16x8*)&Lt[n * 40 + cip];
    *(bf16x8*)&xt[((size_t)b * NSP + n0 + n) * CCH + ci0 + cip] = r;
  }
}

// ============ Pre-pass B: conv_w fp32 [co][ci][9] -> wt bf16 [pos][co][ci] ==
__global__ __launch_bounds__(256) void k_wt(const float* __restrict__ cw,
    __bf16* __restrict__ wt)
{
  const int co = blockIdx.x, ci = threadIdx.x;
  const float* rd = cw + ((size_t)co * CCH + ci) * 9;
#pragma unroll
  for (int p = 0; p < 9; ++p)
    wt[((size_t)p * CCH + co) * CCH + ci] = (__bf16)rd[p];
}

// ============ K1: conv3x3 as implicit GEMM on MFMA =========================
// Block: 64 co x 128 n; 4 waves (each 64co x 32n). K = 8 ci-chunks x 9 taps.
// Xl stages a 6-row x 50-col padded window (zero-filled halo), ci-contiguous.
#define XLP 40   // padded ci stride (80B rows: 2-way max on b128 reads)

__global__ __launch_bounds__(256) void k_conv_mfma(const __bf16* __restrict__ xt,
    const __bf16* __restrict__ wt,
    const float* __restrict__ cb, const float* __restrict__ g,
    const float* __restrict__ be, const float* __restrict__ mu,
    const float* __restrict__ va, float* __restrict__ x1)
{
  __shared__ __bf16 Xl[300 * XLP];      // 24000 B
  __shared__ __bf16 Wl[9 * 64 * XLP];   // 46080 B
  __shared__ float bn[64][2];
  int bid = blockIdx.x;
  const int nt = bid % 18; bid /= 18;
  const int cot = bid % 4; const int b = bid / 4;
  const int n0 = nt * 128, co0 = cot * 64;
  const int tid = threadIdx.x;
  const int w = tid >> 6, l = tid & 63, h = l >> 5, q = l & 31;
  const int ybase0 = n0 / 48;
  const int y0b = ybase0 - 1;           // Xl row r <-> input row y0b + r

  if (tid < 64) {
    const int co = co0 + tid;
    const float inv = g[co] * rsqrtf(va[co] + 1e-5f);
    bn[tid][0] = inv;
    bn[tid][1] = (cb[co] - mu[co]) * inv + be[co];
  }

  // per-lane spatial base for B-frag reads
  const int nabs = n0 + w * 32 + q;
  const int yab = nabs / 48, xab = nabs - yab * 48;
  const int sb = (yab - ybase0) * 50 + xab;   // tap (dy,dx) -> sb + dy*50 + dx

  const __bf16* xtb = xt + (size_t)b * NSP * CCH;

  f32x16 acc0, acc1;
#pragma unroll
  for (int r = 0; r < 16; ++r) { acc0[r] = 0.f; acc1[r] = 0.f; }

  for (int cc = 0; cc < 8; ++cc) {
    __syncthreads();
    // ---- stage Xl: 300 spatial x 32 ci (1200 vec8), zero-filled halo
#pragma unroll
    for (int it = 0; it < 5; ++it) {
      const int v = it * 256 + tid;
      if (v < 1200) {
        const int sp = v >> 2, cip = (v & 3) * 8;
        const int r = sp / 50, xp = sp - r * 50;
        const int gy = y0b + r, gx = xp - 1;
        bf16x8 val;
#pragma unroll
        for (int j = 0; j < 8; ++j) val[j] = (__bf16)0.f;
        if ((unsigned)gy < 48u && (unsigned)gx < 48u)
          val = *(const bf16x8*)&xtb[(size_t)(gy * 48 + gx) * CCH + cc * 32 + cip];
        *(bf16x8*)&Xl[sp * XLP + cip] = val;
      }
    }
    // ---- stage Wl: 9 taps x 64 co x 32 ci
    {
      const int co = tid >> 2, cip = (tid & 3) * 8;
      const __bf16* wsrc = wt + (size_t)(co0 + co) * CCH + cc * 32 + cip;
#pragma unroll
      for (int p = 0; p < 9; ++p) {
        bf16x8 wv = *(const bf16x8*)&wsrc[(size_t)p * CCH * CCH];
        *(bf16x8*)&Wl[(p * 64 + co) * XLP + cip] = wv;
      }
    }
    __syncthreads();
    // ---- compute: 9 taps x 2 k-halves; 4 MFMA per tap per wave
#pragma unroll
    for (int p = 0; p < 9; ++p) {
      const int dy = p / 3, dx = p - 3 * (p / 3);
#pragma unroll
      for (int ks = 0; ks < 2; ++ks) {
        bf16x8 a0 = *(bf16x8*)&Wl[(p * 64 + q) * XLP + ks * 16 + 8 * h];
        bf16x8 a1 = *(bf16x8*)&Wl[(p * 64 + 32 + q) * XLP + ks * 16 + 8 * h];
        bf16x8 bf = *(bf16x8*)&Xl[(sb + dy * 50 + dx) * XLP + ks * 16 + 8 * h];
        acc0 = __builtin_amdgcn_mfma_f32_32x32x16_bf16(a0, bf, acc0, 0, 0, 0);
        acc1 = __builtin_amdgcn_mfma_f32_32x32x16_bf16(a1, bf, acc1, 0, 0, 0);
      }
    }
  }

  // ---- epilogue: BN + ReLU, fp32 store
  float* op = x1 + ((size_t)b * CCH + co0) * NSP + nabs;
#pragma unroll
  for (int r = 0; r < 16; ++r) {
    const int cl = (r & 3) + 8 * (r >> 2) + 4 * h;   // co within 32-block
    op[(size_t)cl * NSP]        = fmaxf(fmaf(acc0[r], bn[cl][0],      bn[cl][1]),      0.f);
    op[(size_t)(32 + cl) * NSP] = fmaxf(fmaf(acc1[r], bn[32 + cl][0], bn[32 + cl][1]), 0.f);
  }
}

// ---------------- K2/K4: 16xK GEMM; MODE 0 -> qkv transposed store ----------
template<int MODE>
__global__ __launch_bounds__(128) void k_gemm(const float* __restrict__ X,
    const float* __restrict__ Wm, const float* __restrict__ bias,
    float* __restrict__ Y, int OT)
{
  __shared__ float wl[16][17];
  __shared__ float xl[16][256];
  const int tid = threadIdx.x;
  int bid = blockIdx.x;
  const int nt = bid % 9; bid /= 9;
  const int ot = bid % OT; const int b = bid / OT;
  const int o0 = ot*16, n0 = nt*256;

  float a0[16], a1[16];
#pragma unroll
  for (int i = 0; i < 16; ++i) { a0[i] = 0.f; a1[i] = 0.f; }

  const float* xb = X + b*CCH*NSP + n0;
  for (int c0 = 0; c0 < CCH; c0 += 16) {
    __syncthreads();
#pragma unroll
    for (int t = 0; t < 2; ++t) {
      int idx = t*128 + tid;
      wl[idx >> 4][idx & 15] = Wm[(o0 + (idx >> 4))*CCH + c0 + (idx & 15)];
    }
#pragma unroll
    for (int r = 0; r < 16; ++r) {
      xl[r][tid]     = xb[(c0 + r)*NSP + tid];
      xl[r][tid+128] = xb[(c0 + r)*NSP + tid + 128];
    }
    __syncthreads();
#pragma unroll
    for (int cc = 0; cc < 16; ++cc) {
      const float xv0 = xl[cc][tid];
      const float xv1 = xl[cc][tid+128];
#pragma unroll
      for (int oo = 0; oo < 16; ++oo) {
        const float w = wl[oo][cc];
        a0[oo] = fmaf(w, xv0, a0[oo]);
        a1[oo] = fmaf(w, xv1, a1[oo]);
      }
    }
  }

  if (MODE == 0) {
    const int head = o0 / 96, rem = o0 % 96;
    const int comp = rem >> 5, e0 = rem & 31;
    float* yb = Y + (size_t)((b*NHEAD + head)*3 + comp)*NSP*DH + e0;
    float* y0 = yb + (size_t)(n0 + tid)*DH;
    float* y1 = yb + (size_t)(n0 + tid + 128)*DH;
#pragma unroll
    for (int oo = 0; oo < 16; ++oo) {
      const float bv = bias[o0 + oo];
      y0[oo] = a0[oo] + bv;
      y1[oo] = a1[oo] + bv;
    }
  } else {
    float* yb = Y + (size_t)b*CCH*NSP + n0 + tid;
#pragma unroll
    for (int oo = 0; oo < 16; ++oo) {
      const float bv = bias[o0 + oo];
      yb[(size_t)(o0+oo)*NSP]       = a0[oo] + bv;
      yb[(size_t)(o0+oo)*NSP + 128] = a1[oo] + bv;
    }
  }
}

// ---------------- K3: MFMA flash attention ---------------------------------
#define KLS 40
#define VLS 72
#define NSTEP 36

static __device__ __forceinline__ unsigned cvtpk(float lo, float hi) {
  unsigned r;
  asm("v_cvt_pk_bf16_f32 %0, %1, %2" : "=v"(r) : "v"(lo), "v"(hi));
  return r;
}

__global__ __launch_bounds__(256) void k_attn_mfma(const float* __restrict__ qkvt,
    float* __restrict__ x2)
{
  __shared__ __bf16 K_lds[64 * KLS];
  __shared__ __bf16 Vt_lds[32 * VLS];
  const int tid = threadIdx.x;
  const int bid0 = blockIdx.x;
  const int bid = (bid0 & 7) * 72 + (bid0 >> 3);
  const int bh = bid / 18;
  const int qb = bid % 18;
  const int w  = tid >> 6;
  const int l  = tid & 63;
  const int h  = l >> 5;
  const int q  = l & 31;

  const float* qg = qkvt + ((size_t)bh * 3    ) * NSP * DH;
  const float* kg = qkvt + ((size_t)bh * 3 + 1) * NSP * DH;
  const float* vg = qkvt + ((size_t)bh * 3 + 2) * NSP * DH;

  const float qsc = 1.4426950408889634f * 0.17677669529663687f;
  const int nq = qb * 128 + w * 32 + q;
  bf16x8 qf0, qf1;
  {
    const float* qp = qg + (size_t)nq * DH + 8 * h;
    float4 t0 = *(const float4*)qp;
    float4 t1 = *(const float4*)(qp + 4);
    qf0[0]=(__bf16)(t0.x*qsc); qf0[1]=(__bf16)(t0.y*qsc); qf0[2]=(__bf16)(t0.z*qsc); qf0[3]=(__bf16)(t0.w*qsc);
    qf0[4]=(__bf16)(t1.x*qsc); qf0[5]=(__bf16)(t1.y*qsc); qf0[6]=(__bf16)(t1.z*qsc); qf0[7]=(__bf16)(t1.w*qsc);
    const float* qp1 = qp + 16;
    float4 t2 = *(const float4*)qp1;
    float4 t3 = *(const float4*)(qp1 + 4);
    qf1[0]=(__bf16)(t2.x*qsc); qf1[1]=(__bf16)(t2.y*qsc); qf1[2]=(__bf16)(t2.z*qsc); qf1[3]=(__bf16)(t2.w*qsc);
    qf1[4]=(__bf16)(t3.x*qsc); qf1[5]=(__bf16)(t3.y*qsc); qf1[6]=(__bf16)(t3.z*qsc); qf1[7]=(__bf16)(t3.w*qsc);
  }

  f32x16 acc0, acc1;
#pragma unroll
  for (int r = 0; r < 16; ++r) { acc0[r] = 0.f; acc1[r] = 0.f; }
  float rs = 0.f;

  const int krow = tid >> 2, kcol = (tid & 3) * 8;
  const int vrow = tid & 63, vcol = (tid >> 6) * 8;

  float4 ka0, ka1, va0, va1;
  {
    const float* kp = kg + (size_t)krow * DH + kcol;
    ka0 = *(const float4*)kp;  ka1 = *(const float4*)(kp + 4);
    const float* vp = vg + (size_t)vrow * DH + vcol;
    va0 = *(const float4*)vp;  va1 = *(const float4*)(vp + 4);
  }

  for (int s = 0; s < NSTEP; ++s) {
    __syncthreads();
    {
      bf16x8 f;
      f[0]=(__bf16)ka0.x; f[1]=(__bf16)ka0.y; f[2]=(__bf16)ka0.z; f[3]=(__bf16)ka0.w;
      f[4]=(__bf16)ka1.x; f[5]=(__bf16)ka1.y; f[6]=(__bf16)ka1.z; f[7]=(__bf16)ka1.w;
      *(bf16x8*)&K_lds[krow * KLS + kcol] = f;
      Vt_lds[(vcol+0)*VLS + vrow] = (__bf16)va0.x;
      Vt_lds[(vcol+1)*VLS + vrow] = (__bf16)va0.y;
      Vt_lds[(vcol+2)*VLS + vrow] = (__bf16)va0.z;
      Vt_lds[(vcol+3)*VLS + vrow] = (__bf16)va0.w;
      Vt_lds[(vcol+4)*VLS + vrow] = (__bf16)va1.x;
      Vt_lds[(vcol+5)*VLS + vrow] = (__bf16)va1.y;
      Vt_lds[(vcol+6)*VLS + vrow] = (__bf16)va1.z;
      Vt_lds[(vcol+7)*VLS + vrow] = (__bf16)va1.w;
    }
    __syncthreads();
    if (s + 1 < NSTEP) {
      const int m1 = (s + 1) * 64;
      const float* kp = kg + (size_t)(m1 + krow) * DH + kcol;
      ka0 = *(const float4*)kp;  ka1 = *(const float4*)(kp + 4);
      const float* vp = vg + (size_t)(m1 + vrow) * DH + vcol;
      va0 = *(const float4*)vp;  va1 = *(const float4*)(vp + 4);
    }
#pragma unroll
    for (int kt = 0; kt < 2; ++kt) {
      bf16x8 kfr0 = *(bf16x8*)&K_lds[(32*kt + q) * KLS + 8*h];
      bf16x8 kfr1 = *(bf16x8*)&K_lds[(32*kt + q) * KLS + 16 + 8*h];
      f32x16 sv;
#pragma unroll
      for (int r = 0; r < 16; ++r) sv[r] = 0.f;
      sv = __builtin_amdgcn_mfma_f32_32x32x16_bf16(kfr0, qf0, sv, 0, 0, 0);
      sv = __builtin_amdgcn_mfma_f32_32x32x16_bf16(kfr1, qf1, sv, 0, 0, 0);
      float p[16];
#pragma unroll
      for (int r = 0; r < 16; ++r) { p[r] = exp2f(sv[r]); rs += p[r]; }
#pragma unroll
      for (int m = 0; m < 2; ++m) {
        unsigned pk00 = cvtpk(p[8*m+0], p[8*m+1]);
        unsigned pk01 = cvtpk(p[8*m+2], p[8*m+3]);
        unsigned pk10 = cvtpk(p[8*m+4], p[8*m+5]);
        unsigned pk11 = cvtpk(p[8*m+6], p[8*m+7]);
        asm("v_permlane32_swap_b32 %0, %1" : "+v"(pk00), "+v"(pk10));
        asm("v_permlane32_swap_b32 %0, %1" : "+v"(pk01), "+v"(pk11));
        u32x4 pw = {pk00, pk01, pk10, pk11};
        bf16x8 pfr = __builtin_bit_cast(bf16x8, pw);
        const int MT = 2*kt + m;
        bf16x8 vfr = *(bf16x8*)&Vt_lds[q * VLS + 16*MT + 8*h];
        if (MT & 1) acc1 = __builtin_amdgcn_mfma_f32_32x32x16_bf16(vfr, pfr, acc1, 0, 0, 0);
        else        acc0 = __builtin_amdgcn_mfma_f32_32x32x16_bf16(vfr, pfr, acc0, 0, 0, 0);
      }
    }
  }

  rs += __shfl_xor(rs, 32, 64);
  const float rn = 1.f / rs;

  float* ob = x2 + (size_t)bh * DH * NSP + nq;
#pragma unroll
  for (int r = 0; r < 16; ++r) {
    const int e = (r & 3) + 8 * (r >> 2) + 4 * h;
    ob[(size_t)e * NSP] = (acc0[r] + acc1[r]) * rn;
  }
}

// ---------------------------------------------------------------------------
extern "C" void kernel_launch(void* const* d_in, const int* in_sizes, int n_in,
                              void* d_out, int out_size, void* d_ws, size_t ws_size,
                              hipStream_t stream)
{
  const float* Vx = (const float*)d_in[0];
  const float* cw = (const float*)d_in[1];
  const float* cb = (const float*)d_in[2];
  const float* g  = (const float*)d_in[3];
  const float* be = (const float*)d_in[4];
  const float* mu = (const float*)d_in[5];
  const float* va = (const float*)d_in[6];
  const float* qw = (const float*)d_in[7];
  const float* qb = (const float*)d_in[8];
  const float* pw = (const float*)d_in[9];
  const float* pb = (const float*)d_in[10];
  float* out = (float*)d_out;
  float* ws  = (float*)d_ws;

  float* x1   = ws;                        // 2359296 f (reused as x2)
  float* qkvt = ws + 2359296;              // 7077888 f

  // d_out doubles as scratch for bf16 pre-transposed conv operands
  // (dead until k_gemm<1> writes the final output).
  __bf16* xt = (__bf16*)d_out;                       // 2359296 bf16 = 4.5 MiB
  __bf16* wt = (__bf16*)((char*)d_out + 4718592);    // 589824 bf16 = 1.1 MiB

  k_xt<<<1152, 256, 0, stream>>>(Vx, xt);
  k_wt<<<256, 256, 0, stream>>>(cw, wt);
  k_conv_mfma<<<288, 256, 0, stream>>>(xt, wt, cb, g, be, mu, va, x1);
  k_gemm<0><<<4*48*9, 128, 0, stream>>>(x1, qw, qb, qkvt, 48);

  float* x2 = x1;   // x1 dead after QKV
  k_attn_mfma<<<576, 256, 0, stream>>>(qkvt, x2);

  k_gemm<1><<<4*16*9, 128, 0, stream>>>(x2, pw, pb, out, 16);
}

// Round 5
// 148.514 us; speedup vs baseline: 9.1508x; 1.8293x over previous
//
#include <hip/hip_runtime.h>
#include <math.h>

#define BB 4
#define CCH 256
#define NSP 2304   // 48*48
#define NHEAD 8
#define DH 32

typedef __bf16 bf16x8 __attribute__((ext_vector_type(8)));
typedef float f32x16 __attribute__((ext_vector_type(16)));
typedef unsigned u32x2 __attribute__((ext_vector_type(2)));
typedef unsigned u32x4 __attribute__((ext_vector_type(4)));

static __device__ __forceinline__ unsigned cvtpk(float lo, float hi) {
  unsigned r;
  asm("v_cvt_pk_bf16_f32 %0, %1, %2" : "=v"(r) : "v"(lo), "v"(hi));
  return r;
}

// ============ Pre-pass A: Vx fp32 [b][ci][n] -> xt bf16 [b][n][ci] =========
__global__ __launch_bounds__(256) void k_xt(const float* __restrict__ Vx,
    __bf16* __restrict__ xt)
{
  __shared__ __bf16 Lt[64 * 40];
  int bid = blockIdx.x;
  const int nt = bid % 36; bid /= 36;
  const int cit = bid % 8; const int b = bid / 8;
  const int n0 = nt * 64, ci0 = cit * 32;
  const int tid = threadIdx.x;
  {
    const int ci = tid >> 3, ns = (tid & 7) * 8;
    const float* src = Vx + ((size_t)(b * CCH + ci0 + ci)) * NSP + n0 + ns;
    float4 v0 = *(const float4*)src;
    float4 v1 = *(const float4*)(src + 4);
    Lt[(ns+0)*40 + ci] = (__bf16)v0.x;  Lt[(ns+1)*40 + ci] = (__bf16)v0.y;
    Lt[(ns+2)*40 + ci] = (__bf16)v0.z;  Lt[(ns+3)*40 + ci] = (__bf16)v0.w;
    Lt[(ns+4)*40 + ci] = (__bf16)v1.x;  Lt[(ns+5)*40 + ci] = (__bf16)v1.y;
    Lt[(ns+6)*40 + ci] = (__bf16)v1.z;  Lt[(ns+7)*40 + ci] = (__bf16)v1.w;
  }
  __syncthreads();
  {
    const int n = tid >> 2, cip = (tid & 3) * 8;
    bf16x8 r = *(bf16x8*)&Lt[n * 40 + cip];
    *(bf16x8*)&xt[((size_t)b * NSP + n0 + n) * CCH + ci0 + cip] = r;
  }
}

// ============ Pre-pass B: conv_w fp32 [co][ci][9] -> wt bf16 [pos][co][ci] ==
__global__ __launch_bounds__(256) void k_wt(const float* __restrict__ cw,
    __bf16* __restrict__ wt)
{
  const int co = blockIdx.x, ci = threadIdx.x;
  const float* rd = cw + ((size_t)co * CCH + ci) * 9;
#pragma unroll
  for (int p = 0; p < 9; ++p)
    wt[((size_t)p * CCH + co) * CCH + ci] = (__bf16)rd[p];
}

// ============ K1: conv3x3 as implicit GEMM on MFMA =========================
// Block: 64 co x 128 n; 4 waves. Output: xq bf16 [b][n][256] (BN+ReLU fused).
#define XLP 40

__global__ __launch_bounds__(256) void k_conv_mfma(const __bf16* __restrict__ xt,
    const __bf16* __restrict__ wt,
    const float* __restrict__ cb, const float* __restrict__ g,
    const float* __restrict__ be, const float* __restrict__ mu,
    const float* __restrict__ va, __bf16* __restrict__ xq)
{
  __shared__ __bf16 Xl[300 * XLP];
  __shared__ __bf16 Wl[9 * 64 * XLP];
  __shared__ float bn[64][2];
  int bid = blockIdx.x;
  const int nt = bid % 18; bid /= 18;
  const int cot = bid % 4; const int b = bid / 4;
  const int n0 = nt * 128, co0 = cot * 64;
  const int tid = threadIdx.x;
  const int w = tid >> 6, l = tid & 63, h = l >> 5, q = l & 31;
  const int ybase0 = n0 / 48;
  const int y0b = ybase0 - 1;

  if (tid < 64) {
    const int co = co0 + tid;
    const float inv = g[co] * rsqrtf(va[co] + 1e-5f);
    bn[tid][0] = inv;
    bn[tid][1] = (cb[co] - mu[co]) * inv + be[co];
  }

  const int nabs = n0 + w * 32 + q;
  const int yab = nabs / 48, xab = nabs - yab * 48;
  const int sb = (yab - ybase0) * 50 + xab;

  const __bf16* xtb = xt + (size_t)b * NSP * CCH;

  f32x16 acc0, acc1;
#pragma unroll
  for (int r = 0; r < 16; ++r) { acc0[r] = 0.f; acc1[r] = 0.f; }

  for (int cc = 0; cc < 8; ++cc) {
    __syncthreads();
#pragma unroll
    for (int it = 0; it < 5; ++it) {
      const int v = it * 256 + tid;
      if (v < 1200) {
        const int sp = v >> 2, cip = (v & 3) * 8;
        const int r = sp / 50, xp = sp - r * 50;
        const int gy = y0b + r, gx = xp - 1;
        bf16x8 val;
#pragma unroll
        for (int j = 0; j < 8; ++j) val[j] = (__bf16)0.f;
        if ((unsigned)gy < 48u && (unsigned)gx < 48u)
          val = *(const bf16x8*)&xtb[(size_t)(gy * 48 + gx) * CCH + cc * 32 + cip];
        *(bf16x8*)&Xl[sp * XLP + cip] = val;
      }
    }
    {
      const int co = tid >> 2, cip = (tid & 3) * 8;
      const __bf16* wsrc = wt + (size_t)(co0 + co) * CCH + cc * 32 + cip;
#pragma unroll
      for (int p = 0; p < 9; ++p) {
        bf16x8 wv = *(const bf16x8*)&wsrc[(size_t)p * CCH * CCH];
        *(bf16x8*)&Wl[(p * 64 + co) * XLP + cip] = wv;
      }
    }
    __syncthreads();
#pragma unroll
    for (int p = 0; p < 9; ++p) {
      const int dy = p / 3, dx = p - 3 * (p / 3);
#pragma unroll
      for (int ks = 0; ks < 2; ++ks) {
        bf16x8 a0 = *(bf16x8*)&Wl[(p * 64 + q) * XLP + ks * 16 + 8 * h];
        bf16x8 a1 = *(bf16x8*)&Wl[(p * 64 + 32 + q) * XLP + ks * 16 + 8 * h];
        bf16x8 bf = *(bf16x8*)&Xl[(sb + dy * 50 + dx) * XLP + ks * 16 + 8 * h];
        acc0 = __builtin_amdgcn_mfma_f32_32x32x16_bf16(a0, bf, acc0, 0, 0, 0);
        acc1 = __builtin_amdgcn_mfma_f32_32x32x16_bf16(a1, bf, acc1, 0, 0, 0);
      }
    }
  }

  // ---- epilogue: BN + ReLU, bf16 store to [b][n][c]
  __bf16* op = xq + ((size_t)b * NSP + nabs) * CCH + co0;
#pragma unroll
  for (int gg = 0; gg < 4; ++gg) {
    const int cl0 = 8 * gg + 4 * h;
    float v0 = fmaxf(fmaf(acc0[4*gg+0], bn[cl0+0][0], bn[cl0+0][1]), 0.f);
    float v1 = fmaxf(fmaf(acc0[4*gg+1], bn[cl0+1][0], bn[cl0+1][1]), 0.f);
    float v2 = fmaxf(fmaf(acc0[4*gg+2], bn[cl0+2][0], bn[cl0+2][1]), 0.f);
    float v3 = fmaxf(fmaf(acc0[4*gg+3], bn[cl0+3][0], bn[cl0+3][1]), 0.f);
    u32x2 pk; pk[0] = cvtpk(v0, v1); pk[1] = cvtpk(v2, v3);
    *(u32x2*)&op[cl0] = pk;
    float w0 = fmaxf(fmaf(acc1[4*gg+0], bn[32+cl0+0][0], bn[32+cl0+0][1]), 0.f);
    float w1 = fmaxf(fmaf(acc1[4*gg+1], bn[32+cl0+1][0], bn[32+cl0+1][1]), 0.f);
    float w2 = fmaxf(fmaf(acc1[4*gg+2], bn[32+cl0+2][0], bn[32+cl0+2][1]), 0.f);
    float w3 = fmaxf(fmaf(acc1[4*gg+3], bn[32+cl0+3][0], bn[32+cl0+3][1]), 0.f);
    u32x2 qk; qk[0] = cvtpk(w0, w1); qk[1] = cvtpk(w2, w3);
    *(u32x2*)&op[32 + cl0] = qk;
  }
}

// ============ K2/K4: MFMA GEMM (64o x 128n tile, 4 waves) ==================
// X bf16 [b][n][256]; W fp32 [o][256] converted inline.
// MODE 0: Y = qkv bf16 [(b*8+head)*3+comp][n][32], +bias
// MODE 1: Y = out fp32 [b][o][n], +bias
template<int MODE>
__global__ __launch_bounds__(256) void k_gemm_mfma(const __bf16* __restrict__ X,
    const float* __restrict__ Wm, const float* __restrict__ bias,
    void* __restrict__ Yv, int OT)
{
  __shared__ __bf16 Xl[128 * XLP];   // 10240 B
  __shared__ __bf16 Wl[64 * XLP];    //  5120 B
  const int tid = threadIdx.x;
  int bid = blockIdx.x;
  const int nt = bid % 18; bid /= 18;
  const int ot = bid % OT; const int b = bid / OT;
  const int o0 = ot * 64, n0 = nt * 128;
  const int w = tid >> 6, l = tid & 63, h = l >> 5, q = l & 31;

  const int xrow = tid >> 1, xcip = (tid & 1) * 16;
  const int wrow = tid >> 2, wcip = (tid & 3) * 8;
  const __bf16* Xb = X + (size_t)b * NSP * CCH + (size_t)(n0 + xrow) * CCH;

  f32x16 acc0, acc1;
#pragma unroll
  for (int r = 0; r < 16; ++r) { acc0[r] = 0.f; acc1[r] = 0.f; }

  bf16x8 xa0, xa1; float4 wa0, wa1;
  xa0 = *(const bf16x8*)&Xb[xcip];
  xa1 = *(const bf16x8*)&Xb[xcip + 8];
  wa0 = *(const float4*)&Wm[(size_t)(o0 + wrow) * CCH + wcip];
  wa1 = *(const float4*)&Wm[(size_t)(o0 + wrow) * CCH + wcip + 4];

  for (int cc = 0; cc < 8; ++cc) {
    __syncthreads();
    *(bf16x8*)&Xl[xrow * XLP + xcip]     = xa0;
    *(bf16x8*)&Xl[xrow * XLP + xcip + 8] = xa1;
    {
      bf16x8 wv;
      wv[0]=(__bf16)wa0.x; wv[1]=(__bf16)wa0.y; wv[2]=(__bf16)wa0.z; wv[3]=(__bf16)wa0.w;
      wv[4]=(__bf16)wa1.x; wv[5]=(__bf16)wa1.y; wv[6]=(__bf16)wa1.z; wv[7]=(__bf16)wa1.w;
      *(bf16x8*)&Wl[wrow * XLP + wcip] = wv;
    }
    __syncthreads();
    if (cc < 7) {
      const int c1 = (cc + 1) * 32;
      xa0 = *(const bf16x8*)&Xb[c1 + xcip];
      xa1 = *(const bf16x8*)&Xb[c1 + xcip + 8];
      wa0 = *(const float4*)&Wm[(size_t)(o0 + wrow) * CCH + c1 + wcip];
      wa1 = *(const float4*)&Wm[(size_t)(o0 + wrow) * CCH + c1 + wcip + 4];
    }
#pragma unroll
    for (int ks = 0; ks < 2; ++ks) {
      bf16x8 a0 = *(bf16x8*)&Wl[q * XLP + ks * 16 + 8 * h];
      bf16x8 a1 = *(bf16x8*)&Wl[(32 + q) * XLP + ks * 16 + 8 * h];
      bf16x8 bfr = *(bf16x8*)&Xl[(w * 32 + q) * XLP + ks * 16 + 8 * h];
      acc0 = __builtin_amdgcn_mfma_f32_32x32x16_bf16(a0, bfr, acc0, 0, 0, 0);
      acc1 = __builtin_amdgcn_mfma_f32_32x32x16_bf16(a1, bfr, acc1, 0, 0, 0);
    }
  }

  const int n = n0 + w * 32 + q;
  if (MODE == 0) {
    __bf16* Y = (__bf16*)Yv;
#pragma unroll
    for (int j = 0; j < 2; ++j) {
      const int t = 2 * ot + j;
      const int head = t / 3, comp = t - 3 * (t / 3);
      __bf16* yb = Y + (((size_t)(b * NHEAD + head) * 3 + comp) * NSP + n) * DH;
      const f32x16& A = j ? acc1 : acc0;
#pragma unroll
      for (int gg = 0; gg < 4; ++gg) {
        const int e0 = 8 * gg + 4 * h;
        const int ob = o0 + 32 * j + e0;
        u32x2 pk;
        pk[0] = cvtpk(A[4*gg+0] + bias[ob+0], A[4*gg+1] + bias[ob+1]);
        pk[1] = cvtpk(A[4*gg+2] + bias[ob+2], A[4*gg+3] + bias[ob+3]);
        *(u32x2*)&yb[e0] = pk;
      }
    }
  } else {
    float* Y = (float*)Yv;
#pragma unroll
    for (int j = 0; j < 2; ++j) {
      const f32x16& A = j ? acc1 : acc0;
#pragma unroll
      for (int r = 0; r < 16; ++r) {
        const int e = (r & 3) + 8 * (r >> 2) + 4 * h;
        const int o = o0 + 32 * j + e;
        Y[((size_t)b * CCH + o) * NSP + n] = A[r] + bias[o];
      }
    }
  }
}

// ============ K3: MFMA flash attention (bf16 qkv in, bf16 x2 out) ==========
#define KLS 40
#define VLS 72
#define NSTEP 36

__global__ __launch_bounds__(256) void k_attn_mfma(const __bf16* __restrict__ qkvt,
    __bf16* __restrict__ x2)
{
  __shared__ __bf16 K_lds[64 * KLS];
  __shared__ __bf16 Vt_lds[32 * VLS];
  const int tid = threadIdx.x;
  const int bid0 = blockIdx.x;
  const int bid = (bid0 & 7) * 72 + (bid0 >> 3);
  const int bh = bid / 18;
  const int qb = bid % 18;
  const int w  = tid >> 6;
  const int l  = tid & 63;
  const int h  = l >> 5;
  const int q  = l & 31;

  const __bf16* qg = qkvt + ((size_t)bh * 3    ) * NSP * DH;
  const __bf16* kg = qkvt + ((size_t)bh * 3 + 1) * NSP * DH;
  const __bf16* vg = qkvt + ((size_t)bh * 3 + 2) * NSP * DH;

  const int nq = qb * 128 + w * 32 + q;
  bf16x8 qf0 = *(const bf16x8*)&qg[(size_t)nq * DH + 8 * h];
  bf16x8 qf1 = *(const bf16x8*)&qg[(size_t)nq * DH + 16 + 8 * h];
  const float SC = 1.4426950408889634f * 0.17677669529663687f;

  f32x16 acc0, acc1;
#pragma unroll
  for (int r = 0; r < 16; ++r) { acc0[r] = 0.f; acc1[r] = 0.f; }
  float rs = 0.f;

  const int krow = tid >> 2, kcol = (tid & 3) * 8;
  const int vrow = tid & 63, vcol = (tid >> 6) * 8;

  bf16x8 ka = *(const bf16x8*)&kg[(size_t)krow * DH + kcol];
  bf16x8 va = *(const bf16x8*)&vg[(size_t)vrow * DH + vcol];

  for (int s = 0; s < NSTEP; ++s) {
    __syncthreads();
    *(bf16x8*)&K_lds[krow * KLS + kcol] = ka;
    Vt_lds[(vcol+0)*VLS + vrow] = va[0];
    Vt_lds[(vcol+1)*VLS + vrow] = va[1];
    Vt_lds[(vcol+2)*VLS + vrow] = va[2];
    Vt_lds[(vcol+3)*VLS + vrow] = va[3];
    Vt_lds[(vcol+4)*VLS + vrow] = va[4];
    Vt_lds[(vcol+5)*VLS + vrow] = va[5];
    Vt_lds[(vcol+6)*VLS + vrow] = va[6];
    Vt_lds[(vcol+7)*VLS + vrow] = va[7];
    __syncthreads();
    if (s + 1 < NSTEP) {
      const int m1 = (s + 1) * 64;
      ka = *(const bf16x8*)&kg[(size_t)(m1 + krow) * DH + kcol];
      va = *(const bf16x8*)&vg[(size_t)(m1 + vrow) * DH + vcol];
    }
#pragma unroll
    for (int kt = 0; kt < 2; ++kt) {
      bf16x8 kfr0 = *(bf16x8*)&K_lds[(32*kt + q) * KLS + 8*h];
      bf16x8 kfr1 = *(bf16x8*)&K_lds[(32*kt + q) * KLS + 16 + 8*h];
      f32x16 sv;
#pragma unroll
      for (int r = 0; r < 16; ++r) sv[r] = 0.f;
      sv = __builtin_amdgcn_mfma_f32_32x32x16_bf16(kfr0, qf0, sv, 0, 0, 0);
      sv = __builtin_amdgcn_mfma_f32_32x32x16_bf16(kfr1, qf1, sv, 0, 0, 0);
      float p[16];
#pragma unroll
      for (int r = 0; r < 16; ++r) { p[r] = exp2f(sv[r] * SC); rs += p[r]; }
#pragma unroll
      for (int m = 0; m < 2; ++m) {
        unsigned pk00 = cvtpk(p[8*m+0], p[8*m+1]);
        unsigned pk01 = cvtpk(p[8*m+2], p[8*m+3]);
        unsigned pk10 = cvtpk(p[8*m+4], p[8*m+5]);
        unsigned pk11 = cvtpk(p[8*m+6], p[8*m+7]);
        asm("v_permlane32_swap_b32 %0, %1" : "+v"(pk00), "+v"(pk10));
        asm("v_permlane32_swap_b32 %0, %1" : "+v"(pk01), "+v"(pk11));
        u32x4 pw = {pk00, pk01, pk10, pk11};
        bf16x8 pfr = __builtin_bit_cast(bf16x8, pw);
        const int MT = 2*kt + m;
        bf16x8 vfr = *(bf16x8*)&Vt_lds[q * VLS + 16*MT + 8*h];
        if (MT & 1) acc1 = __builtin_amdgcn_mfma_f32_32x32x16_bf16(vfr, pfr, acc1, 0, 0, 0);
        else        acc0 = __builtin_amdgcn_mfma_f32_32x32x16_bf16(vfr, pfr, acc0, 0, 0, 0);
      }
    }
  }

  rs += __shfl_xor(rs, 32, 64);
  const float rn = 1.f / rs;

  // write bf16 [b][n][c], c = head*32 + e
  const int b = bh >> 3, head = bh & 7;
  __bf16* ob = x2 + ((size_t)b * NSP + nq) * CCH + head * DH;
#pragma unroll
  for (int gg = 0; gg < 4; ++gg) {
    const int e0 = 8 * gg + 4 * h;
    u32x2 pk;
    pk[0] = cvtpk((acc0[4*gg+0] + acc1[4*gg+0]) * rn, (acc0[4*gg+1] + acc1[4*gg+1]) * rn);
    pk[1] = cvtpk((acc0[4*gg+2] + acc1[4*gg+2]) * rn, (acc0[4*gg+3] + acc1[4*gg+3]) * rn);
    *(u32x2*)&ob[e0] = pk;
  }
}

// ---------------------------------------------------------------------------
extern "C" void kernel_launch(void* const* d_in, const int* in_sizes, int n_in,
                              void* d_out, int out_size, void* d_ws, size_t ws_size,
                              hipStream_t stream)
{
  const float* Vx = (const float*)d_in[0];
  const float* cw = (const float*)d_in[1];
  const float* cb = (const float*)d_in[2];
  const float* g  = (const float*)d_in[3];
  const float* be = (const float*)d_in[4];
  const float* mu = (const float*)d_in[5];
  const float* va = (const float*)d_in[6];
  const float* qw = (const float*)d_in[7];
  const float* qb = (const float*)d_in[8];
  const float* pw = (const float*)d_in[9];
  const float* pb = (const float*)d_in[10];
  float* out = (float*)d_out;

  // ws layout (bf16 pipeline): xq 4.5 MiB | x2 4.5 MiB | qkv 13.5 MiB
  __bf16* xq   = (__bf16*)d_ws;
  __bf16* x2   = (__bf16*)((char*)d_ws + 4718592);
  __bf16* qkvt = (__bf16*)((char*)d_ws + 9437184);

  // d_out doubles as scratch for conv operand pre-transposes
  // (dead until k_gemm_mfma<1> writes the final output).
  __bf16* xt = (__bf16*)d_out;                       // 4.5 MiB
  __bf16* wt = (__bf16*)((char*)d_out + 4718592);    // 1.1 MiB

  k_xt<<<1152, 256, 0, stream>>>(Vx, xt);
  k_wt<<<256, 256, 0, stream>>>(cw, wt);
  k_conv_mfma<<<288, 256, 0, stream>>>(xt, wt, cb, g, be, mu, va, xq);
  k_gemm_mfma<0><<<4*12*18, 256, 0, stream>>>(xq, qw, qb, (void*)qkvt, 12);
  k_attn_mfma<<<576, 256, 0, stream>>>(qkvt, x2);
  k_gemm_mfma<1><<<4*4*18, 256, 0, stream>>>(x2, pw, pb, (void*)out, 4);
}

// Round 6
// 143.353 us; speedup vs baseline: 9.4802x; 1.0360x over previous
//
#include <hip/hip_runtime.h>
#include <math.h>

#define BB 4
#define CCH 256
#define NSP 2304   // 48*48
#define NHEAD 8
#define DH 32

typedef __bf16 bf16x8 __attribute__((ext_vector_type(8)));
typedef float f32x16 __attribute__((ext_vector_type(16)));
typedef unsigned u32x2 __attribute__((ext_vector_type(2)));
typedef unsigned u32x4 __attribute__((ext_vector_type(4)));

static __device__ __forceinline__ unsigned cvtpk(float lo, float hi) {
  unsigned r;
  asm("v_cvt_pk_bf16_f32 %0, %1, %2" : "=v"(r) : "v"(lo), "v"(hi));
  return r;
}

// ============ Pre-pass A: Vx fp32 [b][ci][n] -> xt bf16 [b][n][ci] =========
__global__ __launch_bounds__(256) void k_xt(const float* __restrict__ Vx,
    __bf16* __restrict__ xt)
{
  __shared__ __bf16 Lt[64 * 40];
  int bid = blockIdx.x;
  const int nt = bid % 36; bid /= 36;
  const int cit = bid % 8; const int b = bid / 8;
  const int n0 = nt * 64, ci0 = cit * 32;
  const int tid = threadIdx.x;
  {
    const int ci = tid >> 3, ns = (tid & 7) * 8;
    const float* src = Vx + ((size_t)(b * CCH + ci0 + ci)) * NSP + n0 + ns;
    float4 v0 = *(const float4*)src;
    float4 v1 = *(const float4*)(src + 4);
    Lt[(ns+0)*40 + ci] = (__bf16)v0.x;  Lt[(ns+1)*40 + ci] = (__bf16)v0.y;
    Lt[(ns+2)*40 + ci] = (__bf16)v0.z;  Lt[(ns+3)*40 + ci] = (__bf16)v0.w;
    Lt[(ns+4)*40 + ci] = (__bf16)v1.x;  Lt[(ns+5)*40 + ci] = (__bf16)v1.y;
    Lt[(ns+6)*40 + ci] = (__bf16)v1.z;  Lt[(ns+7)*40 + ci] = (__bf16)v1.w;
  }
  __syncthreads();
  {
    const int n = tid >> 2, cip = (tid & 3) * 8;
    bf16x8 r = *(bf16x8*)&Lt[n * 40 + cip];
    *(bf16x8*)&xt[((size_t)b * NSP + n0 + n) * CCH + ci0 + cip] = r;
  }
}

// ============ Pre-pass B: conv_w fp32 [co][ci][9] -> wt bf16 [pos][co][ci] ==
__global__ __launch_bounds__(256) void k_wt(const float* __restrict__ cw,
    __bf16* __restrict__ wt)
{
  const int co = blockIdx.x, ci = threadIdx.x;
  const float* rd = cw + ((size_t)co * CCH + ci) * 9;
#pragma unroll
  for (int p = 0; p < 9; ++p)
    wt[((size_t)p * CCH + co) * CCH + ci] = (__bf16)rd[p];
}

// ============ K1: conv3x3 as implicit GEMM on MFMA =========================
#define XLP 40

__global__ __launch_bounds__(256) void k_conv_mfma(const __bf16* __restrict__ xt,
    const __bf16* __restrict__ wt,
    const float* __restrict__ cb, const float* __restrict__ g,
    const float* __restrict__ be, const float* __restrict__ mu,
    const float* __restrict__ va, __bf16* __restrict__ xq)
{
  __shared__ __bf16 Xl[300 * XLP];
  __shared__ __bf16 Wl[9 * 64 * XLP];
  __shared__ float bn[64][2];
  int bid = blockIdx.x;
  const int nt = bid % 18; bid /= 18;
  const int cot = bid % 4; const int b = bid / 4;
  const int n0 = nt * 128, co0 = cot * 64;
  const int tid = threadIdx.x;
  const int w = tid >> 6, l = tid & 63, h = l >> 5, q = l & 31;
  const int ybase0 = n0 / 48;
  const int y0b = ybase0 - 1;

  if (tid < 64) {
    const int co = co0 + tid;
    const float inv = g[co] * rsqrtf(va[co] + 1e-5f);
    bn[tid][0] = inv;
    bn[tid][1] = (cb[co] - mu[co]) * inv + be[co];
  }

  const int nabs = n0 + w * 32 + q;
  const int yab = nabs / 48, xab = nabs - yab * 48;
  const int sb = (yab - ybase0) * 50 + xab;

  const __bf16* xtb = xt + (size_t)b * NSP * CCH;

  f32x16 acc0, acc1;
#pragma unroll
  for (int r = 0; r < 16; ++r) { acc0[r] = 0.f; acc1[r] = 0.f; }

  for (int cc = 0; cc < 8; ++cc) {
    __syncthreads();
#pragma unroll
    for (int it = 0; it < 5; ++it) {
      const int v = it * 256 + tid;
      if (v < 1200) {
        const int sp = v >> 2, cip = (v & 3) * 8;
        const int r = sp / 50, xp = sp - r * 50;
        const int gy = y0b + r, gx = xp - 1;
        bf16x8 val;
#pragma unroll
        for (int j = 0; j < 8; ++j) val[j] = (__bf16)0.f;
        if ((unsigned)gy < 48u && (unsigned)gx < 48u)
          val = *(const bf16x8*)&xtb[(size_t)(gy * 48 + gx) * CCH + cc * 32 + cip];
        *(bf16x8*)&Xl[sp * XLP + cip] = val;
      }
    }
    {
      const int co = tid >> 2, cip = (tid & 3) * 8;
      const __bf16* wsrc = wt + (size_t)(co0 + co) * CCH + cc * 32 + cip;
#pragma unroll
      for (int p = 0; p < 9; ++p) {
        bf16x8 wv = *(const bf16x8*)&wsrc[(size_t)p * CCH * CCH];
        *(bf16x8*)&Wl[(p * 64 + co) * XLP + cip] = wv;
      }
    }
    __syncthreads();
#pragma unroll
    for (int p = 0; p < 9; ++p) {
      const int dy = p / 3, dx = p - 3 * (p / 3);
#pragma unroll
      for (int ks = 0; ks < 2; ++ks) {
        bf16x8 a0 = *(bf16x8*)&Wl[(p * 64 + q) * XLP + ks * 16 + 8 * h];
        bf16x8 a1 = *(bf16x8*)&Wl[(p * 64 + 32 + q) * XLP + ks * 16 + 8 * h];
        bf16x8 bf = *(bf16x8*)&Xl[(sb + dy * 50 + dx) * XLP + ks * 16 + 8 * h];
        acc0 = __builtin_amdgcn_mfma_f32_32x32x16_bf16(a0, bf, acc0, 0, 0, 0);
        acc1 = __builtin_amdgcn_mfma_f32_32x32x16_bf16(a1, bf, acc1, 0, 0, 0);
      }
    }
  }

  __bf16* op = xq + ((size_t)b * NSP + nabs) * CCH + co0;
#pragma unroll
  for (int gg = 0; gg < 4; ++gg) {
    const int cl0 = 8 * gg + 4 * h;
    float v0 = fmaxf(fmaf(acc0[4*gg+0], bn[cl0+0][0], bn[cl0+0][1]), 0.f);
    float v1 = fmaxf(fmaf(acc0[4*gg+1], bn[cl0+1][0], bn[cl0+1][1]), 0.f);
    float v2 = fmaxf(fmaf(acc0[4*gg+2], bn[cl0+2][0], bn[cl0+2][1]), 0.f);
    float v3 = fmaxf(fmaf(acc0[4*gg+3], bn[cl0+3][0], bn[cl0+3][1]), 0.f);
    u32x2 pk; pk[0] = cvtpk(v0, v1); pk[1] = cvtpk(v2, v3);
    *(u32x2*)&op[cl0] = pk;
    float w0 = fmaxf(fmaf(acc1[4*gg+0], bn[32+cl0+0][0], bn[32+cl0+0][1]), 0.f);
    float w1 = fmaxf(fmaf(acc1[4*gg+1], bn[32+cl0+1][0], bn[32+cl0+1][1]), 0.f);
    float w2 = fmaxf(fmaf(acc1[4*gg+2], bn[32+cl0+2][0], bn[32+cl0+2][1]), 0.f);
    float w3 = fmaxf(fmaf(acc1[4*gg+3], bn[32+cl0+3][0], bn[32+cl0+3][1]), 0.f);
    u32x2 qk; qk[0] = cvtpk(w0, w1); qk[1] = cvtpk(w2, w3);
    *(u32x2*)&op[32 + cl0] = qk;
  }
}

// ============ K2/K4: MFMA GEMM (64o x 128n tile, 4 waves) ==================
// MODE 0: Y = qkv bf16 [(b*8+head)*3+comp][n][32], +bias; Q rows pre-scaled
//         by log2(e)/sqrt(d) so attention needs no per-score multiply.
// MODE 1: Y = out fp32 [b][o][n], +bias
template<int MODE>
__global__ __launch_bounds__(256) void k_gemm_mfma(const __bf16* __restrict__ X,
    const float* __restrict__ Wm, const float* __restrict__ bias,
    void* __restrict__ Yv, int OT)
{
  __shared__ __bf16 Xl[128 * XLP];
  __shared__ __bf16 Wl[64 * XLP];
  const int tid = threadIdx.x;
  int bid = blockIdx.x;
  const int nt = bid % 18; bid /= 18;
  const int ot = bid % OT; const int b = bid / OT;
  const int o0 = ot * 64, n0 = nt * 128;
  const int w = tid >> 6, l = tid & 63, h = l >> 5, q = l & 31;

  const int xrow = tid >> 1, xcip = (tid & 1) * 16;
  const int wrow = tid >> 2, wcip = (tid & 3) * 8;
  const __bf16* Xb = X + (size_t)b * NSP * CCH + (size_t)(n0 + xrow) * CCH;

  f32x16 acc0, acc1;
#pragma unroll
  for (int r = 0; r < 16; ++r) { acc0[r] = 0.f; acc1[r] = 0.f; }

  bf16x8 xa0, xa1; float4 wa0, wa1;
  xa0 = *(const bf16x8*)&Xb[xcip];
  xa1 = *(const bf16x8*)&Xb[xcip + 8];
  wa0 = *(const float4*)&Wm[(size_t)(o0 + wrow) * CCH + wcip];
  wa1 = *(const float4*)&Wm[(size_t)(o0 + wrow) * CCH + wcip + 4];

  for (int cc = 0; cc < 8; ++cc) {
    __syncthreads();
    *(bf16x8*)&Xl[xrow * XLP + xcip]     = xa0;
    *(bf16x8*)&Xl[xrow * XLP + xcip + 8] = xa1;
    {
      bf16x8 wv;
      wv[0]=(__bf16)wa0.x; wv[1]=(__bf16)wa0.y; wv[2]=(__bf16)wa0.z; wv[3]=(__bf16)wa0.w;
      wv[4]=(__bf16)wa1.x; wv[5]=(__bf16)wa1.y; wv[6]=(__bf16)wa1.z; wv[7]=(__bf16)wa1.w;
      *(bf16x8*)&Wl[wrow * XLP + wcip] = wv;
    }
    __syncthreads();
    if (cc < 7) {
      const int c1 = (cc + 1) * 32;
      xa0 = *(const bf16x8*)&Xb[c1 + xcip];
      xa1 = *(const bf16x8*)&Xb[c1 + xcip + 8];
      wa0 = *(const float4*)&Wm[(size_t)(o0 + wrow) * CCH + c1 + wcip];
      wa1 = *(const float4*)&Wm[(size_t)(o0 + wrow) * CCH + c1 + wcip + 4];
    }
#pragma unroll
    for (int ks = 0; ks < 2; ++ks) {
      bf16x8 a0 = *(bf16x8*)&Wl[q * XLP + ks * 16 + 8 * h];
      bf16x8 a1 = *(bf16x8*)&Wl[(32 + q) * XLP + ks * 16 + 8 * h];
      bf16x8 bfr = *(bf16x8*)&Xl[(w * 32 + q) * XLP + ks * 16 + 8 * h];
      acc0 = __builtin_amdgcn_mfma_f32_32x32x16_bf16(a0, bfr, acc0, 0, 0, 0);
      acc1 = __builtin_amdgcn_mfma_f32_32x32x16_bf16(a1, bfr, acc1, 0, 0, 0);
    }
  }

  const int n = n0 + w * 32 + q;
  if (MODE == 0) {
    const float QS = 1.4426950408889634f * 0.17677669529663687f;
    __bf16* Y = (__bf16*)Yv;
#pragma unroll
    for (int j = 0; j < 2; ++j) {
      const int t = 2 * ot + j;
      const int head = t / 3, comp = t - 3 * (t / 3);
      const float sc = (comp == 0) ? QS : 1.0f;
      __bf16* yb = Y + (((size_t)(b * NHEAD + head) * 3 + comp) * NSP + n) * DH;
      const f32x16& A = j ? acc1 : acc0;
#pragma unroll
      for (int gg = 0; gg < 4; ++gg) {
        const int e0 = 8 * gg + 4 * h;
        const int ob = o0 + 32 * j + e0;
        u32x2 pk;
        pk[0] = cvtpk((A[4*gg+0] + bias[ob+0]) * sc, (A[4*gg+1] + bias[ob+1]) * sc);
        pk[1] = cvtpk((A[4*gg+2] + bias[ob+2]) * sc, (A[4*gg+3] + bias[ob+3]) * sc);
        *(u32x2*)&yb[e0] = pk;
      }
    }
  } else {
    float* Y = (float*)Yv;
#pragma unroll
    for (int j = 0; j < 2; ++j) {
      const f32x16& A = j ? acc1 : acc0;
#pragma unroll
      for (int r = 0; r < 16; ++r) {
        const int e = (r & 3) + 8 * (r >> 2) + 4 * h;
        const int o = o0 + 32 * j + e;
        Y[((size_t)b * CCH + o) * NSP + n] = A[r] + bias[o];
      }
    }
  }
}

// ============ K3: MFMA flash attention (bf16 qkv in, bf16 x2 out) ==========
// Q pre-scaled upstream; rowsum computed on the matrix pipe via ones-MFMA
// (A=ones: out[e][q] = sum_k P[k][q] for every e -> rs = rsacc[0], no shfl).
#define KLS 40
#define VLS 72
#define NSTEP 36

__global__ __launch_bounds__(256) void k_attn_mfma(const __bf16* __restrict__ qkvt,
    __bf16* __restrict__ x2)
{
  __shared__ __bf16 K_lds[64 * KLS];
  __shared__ __bf16 Vt_lds[32 * VLS];
  const int tid = threadIdx.x;
  const int bid0 = blockIdx.x;
  const int bid = (bid0 & 7) * 72 + (bid0 >> 3);
  const int bh = bid / 18;
  const int qb = bid % 18;
  const int w  = tid >> 6;
  const int l  = tid & 63;
  const int h  = l >> 5;
  const int q  = l & 31;

  const __bf16* qg = qkvt + ((size_t)bh * 3    ) * NSP * DH;
  const __bf16* kg = qkvt + ((size_t)bh * 3 + 1) * NSP * DH;
  const __bf16* vg = qkvt + ((size_t)bh * 3 + 2) * NSP * DH;

  const int nq = qb * 128 + w * 32 + q;
  bf16x8 qf0 = *(const bf16x8*)&qg[(size_t)nq * DH + 8 * h];
  bf16x8 qf1 = *(const bf16x8*)&qg[(size_t)nq * DH + 16 + 8 * h];

  // loop-invariant constants: zero C-operand, ones A-fragment
  f32x16 zf;
#pragma unroll
  for (int r = 0; r < 16; ++r) zf[r] = 0.f;
  bf16x8 onesA;
#pragma unroll
  for (int j = 0; j < 8; ++j) onesA[j] = (__bf16)1.0f;

  f32x16 acc0, acc1, rsacc;
#pragma unroll
  for (int r = 0; r < 16; ++r) { acc0[r] = 0.f; acc1[r] = 0.f; rsacc[r] = 0.f; }

  const int krow = tid >> 2, kcol = (tid & 3) * 8;
  const int vrow = tid & 63, vcol = (tid >> 6) * 8;

  bf16x8 ka = *(const bf16x8*)&kg[(size_t)krow * DH + kcol];
  bf16x8 va = *(const bf16x8*)&vg[(size_t)vrow * DH + vcol];

  for (int s = 0; s < NSTEP; ++s) {
    __syncthreads();
    *(bf16x8*)&K_lds[krow * KLS + kcol] = ka;
    Vt_lds[(vcol+0)*VLS + vrow] = va[0];
    Vt_lds[(vcol+1)*VLS + vrow] = va[1];
    Vt_lds[(vcol+2)*VLS + vrow] = va[2];
    Vt_lds[(vcol+3)*VLS + vrow] = va[3];
    Vt_lds[(vcol+4)*VLS + vrow] = va[4];
    Vt_lds[(vcol+5)*VLS + vrow] = va[5];
    Vt_lds[(vcol+6)*VLS + vrow] = va[6];
    Vt_lds[(vcol+7)*VLS + vrow] = va[7];
    __syncthreads();
    if (s + 1 < NSTEP) {
      const int m1 = (s + 1) * 64;
      ka = *(const bf16x8*)&kg[(size_t)(m1 + krow) * DH + kcol];
      va = *(const bf16x8*)&vg[(size_t)(m1 + vrow) * DH + vcol];
    }
#pragma unroll
    for (int kt = 0; kt < 2; ++kt) {
      bf16x8 kfr0 = *(bf16x8*)&K_lds[(32*kt + q) * KLS + 8*h];
      bf16x8 kfr1 = *(bf16x8*)&K_lds[(32*kt + q) * KLS + 16 + 8*h];
      f32x16 sv;
      sv = __builtin_amdgcn_mfma_f32_32x32x16_bf16(kfr0, qf0, zf, 0, 0, 0);
      sv = __builtin_amdgcn_mfma_f32_32x32x16_bf16(kfr1, qf1, sv, 0, 0, 0);
      float p[16];
#pragma unroll
      for (int r = 0; r < 16; ++r) p[r] = exp2f(sv[r]);
#pragma unroll
      for (int m = 0; m < 2; ++m) {
        unsigned pk00 = cvtpk(p[8*m+0], p[8*m+1]);
        unsigned pk01 = cvtpk(p[8*m+2], p[8*m+3]);
        unsigned pk10 = cvtpk(p[8*m+4], p[8*m+5]);
        unsigned pk11 = cvtpk(p[8*m+6], p[8*m+7]);
        asm("v_permlane32_swap_b32 %0, %1" : "+v"(pk00), "+v"(pk10));
        asm("v_permlane32_swap_b32 %0, %1" : "+v"(pk01), "+v"(pk11));
        u32x4 pw = {pk00, pk01, pk10, pk11};
        bf16x8 pfr = __builtin_bit_cast(bf16x8, pw);
        const int MT = 2*kt + m;
        bf16x8 vfr = *(bf16x8*)&Vt_lds[q * VLS + 16*MT + 8*h];
        if (MT & 1) acc1 = __builtin_amdgcn_mfma_f32_32x32x16_bf16(vfr, pfr, acc1, 0, 0, 0);
        else        acc0 = __builtin_amdgcn_mfma_f32_32x32x16_bf16(vfr, pfr, acc0, 0, 0, 0);
        rsacc = __builtin_amdgcn_mfma_f32_32x32x16_bf16(onesA, pfr, rsacc, 0, 0, 0);
      }
    }
  }

  const float rn = 1.f / rsacc[0];

  const int b = bh >> 3, head = bh & 7;
  __bf16* ob = x2 + ((size_t)b * NSP + nq) * CCH + head * DH;
#pragma unroll
  for (int gg = 0; gg < 4; ++gg) {
    const int e0 = 8 * gg + 4 * h;
    u32x2 pk;
    pk[0] = cvtpk((acc0[4*gg+0] + acc1[4*gg+0]) * rn, (acc0[4*gg+1] + acc1[4*gg+1]) * rn);
    pk[1] = cvtpk((acc0[4*gg+2] + acc1[4*gg+2]) * rn, (acc0[4*gg+3] + acc1[4*gg+3]) * rn);
    *(u32x2*)&ob[e0] = pk;
  }
}

// ---------------------------------------------------------------------------
extern "C" void kernel_launch(void* const* d_in, const int* in_sizes, int n_in,
                              void* d_out, int out_size, void* d_ws, size_t ws_size,
                              hipStream_t stream)
{
  const float* Vx = (const float*)d_in[0];
  const float* cw = (const float*)d_in[1];
  const float* cb = (const float*)d_in[2];
  const float* g  = (const float*)d_in[3];
  const float* be = (const float*)d_in[4];
  const float* mu = (const float*)d_in[5];
  const float* va = (const float*)d_in[6];
  const float* qw = (const float*)d_in[7];
  const float* qb = (const float*)d_in[8];
  const float* pw = (const float*)d_in[9];
  const float* pb = (const float*)d_in[10];
  float* out = (float*)d_out;

  // ws layout (bf16 pipeline): xq 4.5 MiB | x2 4.5 MiB | qkv 13.5 MiB
  __bf16* xq   = (__bf16*)d_ws;
  __bf16* x2   = (__bf16*)((char*)d_ws + 4718592);
  __bf16* qkvt = (__bf16*)((char*)d_ws + 9437184);

  // d_out doubles as scratch for conv operand pre-transposes
  // (dead until k_gemm_mfma<1> writes the final output).
  __bf16* xt = (__bf16*)d_out;                       // 4.5 MiB
  __bf16* wt = (__bf16*)((char*)d_out + 4718592);    // 1.1 MiB

  k_xt<<<1152, 256, 0, stream>>>(Vx, xt);
  k_wt<<<256, 256, 0, stream>>>(cw, wt);
  k_conv_mfma<<<288, 256, 0, stream>>>(xt, wt, cb, g, be, mu, va, xq);
  k_gemm_mfma<0><<<4*12*18, 256, 0, stream>>>(xq, qw, qb, (void*)qkvt, 12);
  k_attn_mfma<<<576, 256, 0, stream>>>(qkvt, x2);
  k_gemm_mfma<1><<<4*4*18, 256, 0, stream>>>(x2, pw, pb, (void*)out, 4);
}

// Round 7
// 128.855 us; speedup vs baseline: 10.5469x; 1.1125x over previous
//
#include <hip/hip_runtime.h>
#include <math.h>

#define BB 4
#define CCH 256
#define NSP 2304   // 48*48
#define NHEAD 8
#define DH 32

typedef __bf16 bf16x8 __attribute__((ext_vector_type(8)));
typedef float f32x16 __attribute__((ext_vector_type(16)));
typedef unsigned u32x2 __attribute__((ext_vector_type(2)));
typedef unsigned u32x4 __attribute__((ext_vector_type(4)));

static __device__ __forceinline__ unsigned cvtpk(float lo, float hi) {
  unsigned r;
  asm("v_cvt_pk_bf16_f32 %0, %1, %2" : "=v"(r) : "v"(lo), "v"(hi));
  return r;
}

// ============ Pre-pass A: Vx fp32 [b][ci][n] -> xt bf16 [b][n][ci] =========
__global__ __launch_bounds__(256) void k_xt(const float* __restrict__ Vx,
    __bf16* __restrict__ xt)
{
  __shared__ __bf16 Lt[64 * 40];
  int bid = blockIdx.x;
  const int nt = bid % 36; bid /= 36;
  const int cit = bid % 8; const int b = bid / 8;
  const int n0 = nt * 64, ci0 = cit * 32;
  const int tid = threadIdx.x;
  {
    const int ci = tid >> 3, ns = (tid & 7) * 8;
    const float* src = Vx + ((size_t)(b * CCH + ci0 + ci)) * NSP + n0 + ns;
    float4 v0 = *(const float4*)src;
    float4 v1 = *(const float4*)(src + 4);
    Lt[(ns+0)*40 + ci] = (__bf16)v0.x;  Lt[(ns+1)*40 + ci] = (__bf16)v0.y;
    Lt[(ns+2)*40 + ci] = (__bf16)v0.z;  Lt[(ns+3)*40 + ci] = (__bf16)v0.w;
    Lt[(ns+4)*40 + ci] = (__bf16)v1.x;  Lt[(ns+5)*40 + ci] = (__bf16)v1.y;
    Lt[(ns+6)*40 + ci] = (__bf16)v1.z;  Lt[(ns+7)*40 + ci] = (__bf16)v1.w;
  }
  __syncthreads();
  {
    const int n = tid >> 2, cip = (tid & 3) * 8;
    bf16x8 r = *(bf16x8*)&Lt[n * 40 + cip];
    *(bf16x8*)&xt[((size_t)b * NSP + n0 + n) * CCH + ci0 + cip] = r;
  }
}

// ============ Pre-pass B: conv_w fp32 [co][ci][9] -> wt bf16 [pos][co][ci] ==
__global__ __launch_bounds__(256) void k_wt(const float* __restrict__ cw,
    __bf16* __restrict__ wt)
{
  const int co = blockIdx.x, ci = threadIdx.x;
  const float* rd = cw + ((size_t)co * CCH + ci) * 9;
#pragma unroll
  for (int p = 0; p < 9; ++p)
    wt[((size_t)p * CCH + co) * CCH + ci] = (__bf16)rd[p];
}

// ============ K1: conv3x3 as implicit GEMM on MFMA =========================
#define XLP 40

__global__ __launch_bounds__(256) void k_conv_mfma(const __bf16* __restrict__ xt,
    const __bf16* __restrict__ wt,
    const float* __restrict__ cb, const float* __restrict__ g,
    const float* __restrict__ be, const float* __restrict__ mu,
    const float* __restrict__ va, __bf16* __restrict__ xq)
{
  __shared__ __bf16 Xl[300 * XLP];
  __shared__ __bf16 Wl[9 * 64 * XLP];
  __shared__ float bn[64][2];
  int bid = blockIdx.x;
  const int nt = bid % 18; bid /= 18;
  const int cot = bid % 4; const int b = bid / 4;
  const int n0 = nt * 128, co0 = cot * 64;
  const int tid = threadIdx.x;
  const int w = tid >> 6, l = tid & 63, h = l >> 5, q = l & 31;
  const int ybase0 = n0 / 48;
  const int y0b = ybase0 - 1;

  if (tid < 64) {
    const int co = co0 + tid;
    const float inv = g[co] * rsqrtf(va[co] + 1e-5f);
    bn[tid][0] = inv;
    bn[tid][1] = (cb[co] - mu[co]) * inv + be[co];
  }

  const int nabs = n0 + w * 32 + q;
  const int yab = nabs / 48, xab = nabs - yab * 48;
  const int sb = (yab - ybase0) * 50 + xab;

  const __bf16* xtb = xt + (size_t)b * NSP * CCH;

  f32x16 acc0, acc1;
#pragma unroll
  for (int r = 0; r < 16; ++r) { acc0[r] = 0.f; acc1[r] = 0.f; }

  for (int cc = 0; cc < 8; ++cc) {
    __syncthreads();
#pragma unroll
    for (int it = 0; it < 5; ++it) {
      const int v = it * 256 + tid;
      if (v < 1200) {
        const int sp = v >> 2, cip = (v & 3) * 8;
        const int r = sp / 50, xp = sp - r * 50;
        const int gy = y0b + r, gx = xp - 1;
        bf16x8 val;
#pragma unroll
        for (int j = 0; j < 8; ++j) val[j] = (__bf16)0.f;
        if ((unsigned)gy < 48u && (unsigned)gx < 48u)
          val = *(const bf16x8*)&xtb[(size_t)(gy * 48 + gx) * CCH + cc * 32 + cip];
        *(bf16x8*)&Xl[sp * XLP + cip] = val;
      }
    }
    {
      const int co = tid >> 2, cip = (tid & 3) * 8;
      const __bf16* wsrc = wt + (size_t)(co0 + co) * CCH + cc * 32 + cip;
#pragma unroll
      for (int p = 0; p < 9; ++p) {
        bf16x8 wv = *(const bf16x8*)&wsrc[(size_t)p * CCH * CCH];
        *(bf16x8*)&Wl[(p * 64 + co) * XLP + cip] = wv;
      }
    }
    __syncthreads();
#pragma unroll
    for (int p = 0; p < 9; ++p) {
      const int dy = p / 3, dx = p - 3 * (p / 3);
#pragma unroll
      for (int ks = 0; ks < 2; ++ks) {
        bf16x8 a0 = *(bf16x8*)&Wl[(p * 64 + q) * XLP + ks * 16 + 8 * h];
        bf16x8 a1 = *(bf16x8*)&Wl[(p * 64 + 32 + q) * XLP + ks * 16 + 8 * h];
        bf16x8 bf = *(bf16x8*)&Xl[(sb + dy * 50 + dx) * XLP + ks * 16 + 8 * h];
        acc0 = __builtin_amdgcn_mfma_f32_32x32x16_bf16(a0, bf, acc0, 0, 0, 0);
        acc1 = __builtin_amdgcn_mfma_f32_32x32x16_bf16(a1, bf, acc1, 0, 0, 0);
      }
    }
  }

  __bf16* op = xq + ((size_t)b * NSP + nabs) * CCH + co0;
#pragma unroll
  for (int gg = 0; gg < 4; ++gg) {
    const int cl0 = 8 * gg + 4 * h;
    float v0 = fmaxf(fmaf(acc0[4*gg+0], bn[cl0+0][0], bn[cl0+0][1]), 0.f);
    float v1 = fmaxf(fmaf(acc0[4*gg+1], bn[cl0+1][0], bn[cl0+1][1]), 0.f);
    float v2 = fmaxf(fmaf(acc0[4*gg+2], bn[cl0+2][0], bn[cl0+2][1]), 0.f);
    float v3 = fmaxf(fmaf(acc0[4*gg+3], bn[cl0+3][0], bn[cl0+3][1]), 0.f);
    u32x2 pk; pk[0] = cvtpk(v0, v1); pk[1] = cvtpk(v2, v3);
    *(u32x2*)&op[cl0] = pk;
    float w0 = fmaxf(fmaf(acc1[4*gg+0], bn[32+cl0+0][0], bn[32+cl0+0][1]), 0.f);
    float w1 = fmaxf(fmaf(acc1[4*gg+1], bn[32+cl0+1][0], bn[32+cl0+1][1]), 0.f);
    float w2 = fmaxf(fmaf(acc1[4*gg+2], bn[32+cl0+2][0], bn[32+cl0+2][1]), 0.f);
    float w3 = fmaxf(fmaf(acc1[4*gg+3], bn[32+cl0+3][0], bn[32+cl0+3][1]), 0.f);
    u32x2 qk; qk[0] = cvtpk(w0, w1); qk[1] = cvtpk(w2, w3);
    *(u32x2*)&op[32 + cl0] = qk;
  }
}

// ============ K2/K4: MFMA GEMM (64o x 128n tile, 4 waves) ==================
template<int MODE>
__global__ __launch_bounds__(256) void k_gemm_mfma(const __bf16* __restrict__ X,
    const float* __restrict__ Wm, const float* __restrict__ bias,
    void* __restrict__ Yv, int OT)
{
  __shared__ __bf16 Xl[128 * XLP];
  __shared__ __bf16 Wl[64 * XLP];
  const int tid = threadIdx.x;
  int bid = blockIdx.x;
  const int nt = bid % 18; bid /= 18;
  const int ot = bid % OT; const int b = bid / OT;
  const int o0 = ot * 64, n0 = nt * 128;
  const int w = tid >> 6, l = tid & 63, h = l >> 5, q = l & 31;

  const int xrow = tid >> 1, xcip = (tid & 1) * 16;
  const int wrow = tid >> 2, wcip = (tid & 3) * 8;
  const __bf16* Xb = X + (size_t)b * NSP * CCH + (size_t)(n0 + xrow) * CCH;

  f32x16 acc0, acc1;
#pragma unroll
  for (int r = 0; r < 16; ++r) { acc0[r] = 0.f; acc1[r] = 0.f; }

  bf16x8 xa0, xa1; float4 wa0, wa1;
  xa0 = *(const bf16x8*)&Xb[xcip];
  xa1 = *(const bf16x8*)&Xb[xcip + 8];
  wa0 = *(const float4*)&Wm[(size_t)(o0 + wrow) * CCH + wcip];
  wa1 = *(const float4*)&Wm[(size_t)(o0 + wrow) * CCH + wcip + 4];

  for (int cc = 0; cc < 8; ++cc) {
    __syncthreads();
    *(bf16x8*)&Xl[xrow * XLP + xcip]     = xa0;
    *(bf16x8*)&Xl[xrow * XLP + xcip + 8] = xa1;
    {
      bf16x8 wv;
      wv[0]=(__bf16)wa0.x; wv[1]=(__bf16)wa0.y; wv[2]=(__bf16)wa0.z; wv[3]=(__bf16)wa0.w;
      wv[4]=(__bf16)wa1.x; wv[5]=(__bf16)wa1.y; wv[6]=(__bf16)wa1.z; wv[7]=(__bf16)wa1.w;
      *(bf16x8*)&Wl[wrow * XLP + wcip] = wv;
    }
    __syncthreads();
    if (cc < 7) {
      const int c1 = (cc + 1) * 32;
      xa0 = *(const bf16x8*)&Xb[c1 + xcip];
      xa1 = *(const bf16x8*)&Xb[c1 + xcip + 8];
      wa0 = *(const float4*)&Wm[(size_t)(o0 + wrow) * CCH + c1 + wcip];
      wa1 = *(const float4*)&Wm[(size_t)(o0 + wrow) * CCH + c1 + wcip + 4];
    }
#pragma unroll
    for (int ks = 0; ks < 2; ++ks) {
      bf16x8 a0 = *(bf16x8*)&Wl[q * XLP + ks * 16 + 8 * h];
      bf16x8 a1 = *(bf16x8*)&Wl[(32 + q) * XLP + ks * 16 + 8 * h];
      bf16x8 bfr = *(bf16x8*)&Xl[(w * 32 + q) * XLP + ks * 16 + 8 * h];
      acc0 = __builtin_amdgcn_mfma_f32_32x32x16_bf16(a0, bfr, acc0, 0, 0, 0);
      acc1 = __builtin_amdgcn_mfma_f32_32x32x16_bf16(a1, bfr, acc1, 0, 0, 0);
    }
  }

  const int n = n0 + w * 32 + q;
  if (MODE == 0) {
    const float QS = 1.4426950408889634f * 0.17677669529663687f;
    __bf16* Y = (__bf16*)Yv;
#pragma unroll
    for (int j = 0; j < 2; ++j) {
      const int t = 2 * ot + j;
      const int head = t / 3, comp = t - 3 * (t / 3);
      const float sc = (comp == 0) ? QS : 1.0f;
      __bf16* yb = Y + (((size_t)(b * NHEAD + head) * 3 + comp) * NSP + n) * DH;
      const f32x16& A = j ? acc1 : acc0;
#pragma unroll
      for (int gg = 0; gg < 4; ++gg) {
        const int e0 = 8 * gg + 4 * h;
        const int ob = o0 + 32 * j + e0;
        u32x2 pk;
        pk[0] = cvtpk((A[4*gg+0] + bias[ob+0]) * sc, (A[4*gg+1] + bias[ob+1]) * sc);
        pk[1] = cvtpk((A[4*gg+2] + bias[ob+2]) * sc, (A[4*gg+3] + bias[ob+3]) * sc);
        *(u32x2*)&yb[e0] = pk;
      }
    }
  } else {
    float* Y = (float*)Yv;
#pragma unroll
    for (int j = 0; j < 2; ++j) {
      const f32x16& A = j ? acc1 : acc0;
#pragma unroll
      for (int r = 0; r < 16; ++r) {
        const int e = (r & 3) + 8 * (r >> 2) + 4 * h;
        const int o = o0 + 32 * j + e;
        Y[((size_t)b * CCH + o) * NSP + n] = A[r] + bias[o];
      }
    }
  }
}

// ============ K3: MFMA flash attention, K-split x2, double-buffered LDS ====
// 1152 blocks: bid -> (bh, qb, ks). Each block does 1152 keys (18 steps),
// writes UNNORMALIZED partial x2 (bf16) + rowsum (fp32, from ones-MFMA).
// One barrier per step (stage buf^1 || compute buf).
#define KLS 40
#define VLS 72
#define NST 18

__global__ __launch_bounds__(256) void k_attn_mfma(const __bf16* __restrict__ qkvt,
    __bf16* __restrict__ x2parts, float* __restrict__ rss)
{
  __shared__ __bf16 K_lds[2][64 * KLS];
  __shared__ __bf16 Vt_lds[2][32 * VLS];
  const int tid = threadIdx.x;
  const int bid0 = blockIdx.x;
  // XCD swizzle over 1152 = 8 * 144; adjacent pairs (same bh,qb) share XCD
  const int bid = (bid0 & 7) * 144 + (bid0 >> 3);
  const int bh  = bid / 36;
  const int rem = bid % 36;
  const int qb  = rem >> 1;
  const int ks  = rem & 1;
  const int w  = tid >> 6;
  const int l  = tid & 63;
  const int h  = l >> 5;
  const int q  = l & 31;

  const __bf16* qg = qkvt + ((size_t)bh * 3    ) * NSP * DH;
  const __bf16* kg = qkvt + ((size_t)bh * 3 + 1) * NSP * DH;
  const __bf16* vg = qkvt + ((size_t)bh * 3 + 2) * NSP * DH;

  const int nq = qb * 128 + w * 32 + q;
  bf16x8 qf0 = *(const bf16x8*)&qg[(size_t)nq * DH + 8 * h];
  bf16x8 qf1 = *(const bf16x8*)&qg[(size_t)nq * DH + 16 + 8 * h];

  f32x16 zf;
#pragma unroll
  for (int r = 0; r < 16; ++r) zf[r] = 0.f;
  bf16x8 onesA;
#pragma unroll
  for (int j = 0; j < 8; ++j) onesA[j] = (__bf16)1.0f;

  f32x16 acc0, acc1, rsacc;
#pragma unroll
  for (int r = 0; r < 16; ++r) { acc0[r] = 0.f; acc1[r] = 0.f; rsacc[r] = 0.f; }

  const int krow = tid >> 2, kcol = (tid & 3) * 8;
  const int vrow = tid & 63, vcol = (tid >> 6) * 8;
  const int m0 = ks * (NST * 64);

  // ---- prologue: stage step 0 into buf0; preload step-1 regs
  bf16x8 ka = *(const bf16x8*)&kg[(size_t)(m0 + krow) * DH + kcol];
  bf16x8 va = *(const bf16x8*)&vg[(size_t)(m0 + vrow) * DH + vcol];
  *(bf16x8*)&K_lds[0][krow * KLS + kcol] = ka;
#pragma unroll
  for (int j = 0; j < 8; ++j) Vt_lds[0][(vcol + j) * VLS + vrow] = va[j];
  ka = *(const bf16x8*)&kg[(size_t)(m0 + 64 + krow) * DH + kcol];
  va = *(const bf16x8*)&vg[(size_t)(m0 + 64 + vrow) * DH + vcol];
  __syncthreads();

  for (int s = 0; s < NST; ++s) {
    const int cur = s & 1;
    // ---- stage buf^1 for step s+1 (regs loaded during step s-1)
    if (s + 1 < NST) {
      *(bf16x8*)&K_lds[cur ^ 1][krow * KLS + kcol] = ka;
#pragma unroll
      for (int j = 0; j < 8; ++j) Vt_lds[cur ^ 1][(vcol + j) * VLS + vrow] = va[j];
      if (s + 2 < NST) {
        const int m2 = m0 + (s + 2) * 64;
        ka = *(const bf16x8*)&kg[(size_t)(m2 + krow) * DH + kcol];
        va = *(const bf16x8*)&vg[(size_t)(m2 + vrow) * DH + vcol];
      }
    }
    // ---- compute on buf[cur]
#pragma unroll
    for (int kt = 0; kt < 2; ++kt) {
      bf16x8 kfr0 = *(bf16x8*)&K_lds[cur][(32*kt + q) * KLS + 8*h];
      bf16x8 kfr1 = *(bf16x8*)&K_lds[cur][(32*kt + q) * KLS + 16 + 8*h];
      f32x16 sv;
      sv = __builtin_amdgcn_mfma_f32_32x32x16_bf16(kfr0, qf0, zf, 0, 0, 0);
      sv = __builtin_amdgcn_mfma_f32_32x32x16_bf16(kfr1, qf1, sv, 0, 0, 0);
      float p[16];
#pragma unroll
      for (int r = 0; r < 16; ++r) p[r] = exp2f(sv[r]);
#pragma unroll
      for (int m = 0; m < 2; ++m) {
        unsigned pk00 = cvtpk(p[8*m+0], p[8*m+1]);
        unsigned pk01 = cvtpk(p[8*m+2], p[8*m+3]);
        unsigned pk10 = cvtpk(p[8*m+4], p[8*m+5]);
        unsigned pk11 = cvtpk(p[8*m+6], p[8*m+7]);
        asm("v_permlane32_swap_b32 %0, %1" : "+v"(pk00), "+v"(pk10));
        asm("v_permlane32_swap_b32 %0, %1" : "+v"(pk01), "+v"(pk11));
        u32x4 pw = {pk00, pk01, pk10, pk11};
        bf16x8 pfr = __builtin_bit_cast(bf16x8, pw);
        const int MT = 2*kt + m;
        bf16x8 vfr = *(bf16x8*)&Vt_lds[cur][q * VLS + 16*MT + 8*h];
        if (MT & 1) acc1 = __builtin_amdgcn_mfma_f32_32x32x16_bf16(vfr, pfr, acc1, 0, 0, 0);
        else        acc0 = __builtin_amdgcn_mfma_f32_32x32x16_bf16(vfr, pfr, acc0, 0, 0, 0);
        rsacc = __builtin_amdgcn_mfma_f32_32x32x16_bf16(onesA, pfr, rsacc, 0, 0, 0);
      }
    }
    __syncthreads();
  }

  // ---- epilogue: UNNORMALIZED partial + rowsum
  const int b = bh >> 3, head = bh & 7;
  __bf16* ob = x2parts + (size_t)ks * 2359296
             + ((size_t)b * NSP + nq) * CCH + head * DH;
#pragma unroll
  for (int gg = 0; gg < 4; ++gg) {
    const int e0 = 8 * gg + 4 * h;
    u32x2 pk;
    pk[0] = cvtpk(acc0[4*gg+0] + acc1[4*gg+0], acc0[4*gg+1] + acc1[4*gg+1]);
    pk[1] = cvtpk(acc0[4*gg+2] + acc1[4*gg+2], acc0[4*gg+3] + acc1[4*gg+3]);
    *(u32x2*)&ob[e0] = pk;
  }
  if (h == 0)
    rss[(size_t)ks * 73728 + (size_t)bh * NSP + nq] = rsacc[0];
}

// ============ K3b: combine splits -> normalized x2 bf16 [b][n][256] ========
__global__ __launch_bounds__(256) void k_combine(const __bf16* __restrict__ x2parts,
    const float* __restrict__ rss, __bf16* __restrict__ x2)
{
  const int tid = threadIdx.x;
  const int row = blockIdx.x * 16 + (tid >> 4);      // b*NSP + n
  const int cseg = (tid & 15) * 16;
  const int b = row / NSP, n = row - b * NSP;
  const int head = cseg >> 5;
  const size_t ri = (size_t)(b * NHEAD + head) * NSP + n;
  const float rn = 1.f / (rss[ri] + rss[73728 + ri]);

  const size_t base = (size_t)row * CCH + cseg;
  bf16x8 a0 = *(const bf16x8*)&x2parts[base];
  bf16x8 a1 = *(const bf16x8*)&x2parts[base + 8];
  bf16x8 b0 = *(const bf16x8*)&x2parts[2359296 + base];
  bf16x8 b1 = *(const bf16x8*)&x2parts[2359296 + base + 8];
  u32x4 o0, o1;
#pragma unroll
  for (int j = 0; j < 4; ++j) {
    o0[j] = cvtpk(((float)a0[2*j] + (float)b0[2*j]) * rn,
                  ((float)a0[2*j+1] + (float)b0[2*j+1]) * rn);
    o1[j] = cvtpk(((float)a1[2*j] + (float)b1[2*j]) * rn,
                  ((float)a1[2*j+1] + (float)b1[2*j+1]) * rn);
  }
  *(u32x4*)&x2[base] = o0;
  *(u32x4*)&x2[base + 8] = o1;
}

// ---------------------------------------------------------------------------
extern "C" void kernel_launch(void* const* d_in, const int* in_sizes, int n_in,
                              void* d_out, int out_size, void* d_ws, size_t ws_size,
                              hipStream_t stream)
{
  const float* Vx = (const float*)d_in[0];
  const float* cw = (const float*)d_in[1];
  const float* cb = (const float*)d_in[2];
  const float* g  = (const float*)d_in[3];
  const float* be = (const float*)d_in[4];
  const float* mu = (const float*)d_in[5];
  const float* va = (const float*)d_in[6];
  const float* qw = (const float*)d_in[7];
  const float* qb = (const float*)d_in[8];
  const float* pw = (const float*)d_in[9];
  const float* pb = (const float*)d_in[10];
  float* out = (float*)d_out;

  // ws: xq 4.5M | x2 4.5M | qkv 13.5M | x2parts 9M | rss 0.56M  (~32.1 MiB)
  __bf16* xq      = (__bf16*)d_ws;
  __bf16* x2      = (__bf16*)((char*)d_ws + 4718592);
  __bf16* qkvt    = (__bf16*)((char*)d_ws + 9437184);
  __bf16* x2parts = (__bf16*)((char*)d_ws + 23592960);
  float*  rss     = (float*) ((char*)d_ws + 33030144);

  // d_out doubles as scratch for conv operand pre-transposes
  __bf16* xt = (__bf16*)d_out;                       // 4.5 MiB
  __bf16* wt = (__bf16*)((char*)d_out + 4718592);    // 1.1 MiB

  k_xt<<<1152, 256, 0, stream>>>(Vx, xt);
  k_wt<<<256, 256, 0, stream>>>(cw, wt);
  k_conv_mfma<<<288, 256, 0, stream>>>(xt, wt, cb, g, be, mu, va, xq);
  k_gemm_mfma<0><<<4*12*18, 256, 0, stream>>>(xq, qw, qb, (void*)qkvt, 12);
  k_attn_mfma<<<1152, 256, 0, stream>>>(qkvt, x2parts, rss);
  k_combine<<<576, 256, 0, stream>>>(x2parts, rss, x2);
  k_gemm_mfma<1><<<4*4*18, 256, 0, stream>>>(x2, pw, pb, (void*)out, 4);
}

// Round 8
// 113.653 us; speedup vs baseline: 11.9576x; 1.1338x over previous
//
#include <hip/hip_runtime.h>
#include <math.h>

#define BB 4
#define CCH 256
#define NSP 2304   // 48*48
#define NHEAD 8
#define DH 32

typedef __bf16 bf16x8 __attribute__((ext_vector_type(8)));
typedef float f32x16 __attribute__((ext_vector_type(16)));
typedef unsigned u32x2 __attribute__((ext_vector_type(2)));
typedef unsigned u32x4 __attribute__((ext_vector_type(4)));

static __device__ __forceinline__ unsigned cvtpk(float lo, float hi) {
  unsigned r;
  asm("v_cvt_pk_bf16_f32 %0, %1, %2" : "=v"(r) : "v"(lo), "v"(hi));
  return r;
}

#if __has_builtin(__builtin_amdgcn_exp2f)
static __device__ __forceinline__ float fexp2(float x) { return __builtin_amdgcn_exp2f(x); }
#else
static __device__ __forceinline__ float fexp2(float x) { return exp2f(x); }
#endif

#if __has_builtin(__builtin_amdgcn_rcpf)
static __device__ __forceinline__ float frcp(float x) { return __builtin_amdgcn_rcpf(x); }
#else
static __device__ __forceinline__ float frcp(float x) { return 1.f / x; }
#endif

// ============ Pre-pass A: Vx fp32 [b][ci][n] -> xt bf16 [b][n][ci] =========
__global__ __launch_bounds__(256) void k_xt(const float* __restrict__ Vx,
    __bf16* __restrict__ xt)
{
  __shared__ __bf16 Lt[64 * 40];
  int bid = blockIdx.x;
  const int nt = bid % 36; bid /= 36;
  const int cit = bid % 8; const int b = bid / 8;
  const int n0 = nt * 64, ci0 = cit * 32;
  const int tid = threadIdx.x;
  {
    const int ci = tid >> 3, ns = (tid & 7) * 8;
    const float* src = Vx + ((size_t)(b * CCH + ci0 + ci)) * NSP + n0 + ns;
    float4 v0 = *(const float4*)src;
    float4 v1 = *(const float4*)(src + 4);
    Lt[(ns+0)*40 + ci] = (__bf16)v0.x;  Lt[(ns+1)*40 + ci] = (__bf16)v0.y;
    Lt[(ns+2)*40 + ci] = (__bf16)v0.z;  Lt[(ns+3)*40 + ci] = (__bf16)v0.w;
    Lt[(ns+4)*40 + ci] = (__bf16)v1.x;  Lt[(ns+5)*40 + ci] = (__bf16)v1.y;
    Lt[(ns+6)*40 + ci] = (__bf16)v1.z;  Lt[(ns+7)*40 + ci] = (__bf16)v1.w;
  }
  __syncthreads();
  {
    const int n = tid >> 2, cip = (tid & 3) * 8;
    bf16x8 r = *(bf16x8*)&Lt[n * 40 + cip];
    *(bf16x8*)&xt[((size_t)b * NSP + n0 + n) * CCH + ci0 + cip] = r;
  }
}

// ============ Pre-pass B: conv_w fp32 [co][ci][9] -> wt bf16 [pos][co][ci] ==
__global__ __launch_bounds__(256) void k_wt(const float* __restrict__ cw,
    __bf16* __restrict__ wt)
{
  const int co = blockIdx.x, ci = threadIdx.x;
  const float* rd = cw + ((size_t)co * CCH + ci) * 9;
#pragma unroll
  for (int p = 0; p < 9; ++p)
    wt[((size_t)p * CCH + co) * CCH + ci] = (__bf16)rd[p];
}

// ============ K1: conv3x3 as implicit GEMM on MFMA =========================
#define XLP 40

__global__ __launch_bounds__(256) void k_conv_mfma(const __bf16* __restrict__ xt,
    const __bf16* __restrict__ wt,
    const float* __restrict__ cb, const float* __restrict__ g,
    const float* __restrict__ be, const float* __restrict__ mu,
    const float* __restrict__ va, __bf16* __restrict__ xq)
{
  __shared__ __bf16 Xl[300 * XLP];
  __shared__ __bf16 Wl[9 * 64 * XLP];
  __shared__ float bn[64][2];
  int bid = blockIdx.x;
  const int nt = bid % 18; bid /= 18;
  const int cot = bid % 4; const int b = bid / 4;
  const int n0 = nt * 128, co0 = cot * 64;
  const int tid = threadIdx.x;
  const int w = tid >> 6, l = tid & 63, h = l >> 5, q = l & 31;
  const int ybase0 = n0 / 48;
  const int y0b = ybase0 - 1;

  if (tid < 64) {
    const int co = co0 + tid;
    const float inv = g[co] * rsqrtf(va[co] + 1e-5f);
    bn[tid][0] = inv;
    bn[tid][1] = (cb[co] - mu[co]) * inv + be[co];
  }

  const int nabs = n0 + w * 32 + q;
  const int yab = nabs / 48, xab = nabs - yab * 48;
  const int sb = (yab - ybase0) * 50 + xab;

  const __bf16* xtb = xt + (size_t)b * NSP * CCH;

  f32x16 acc0, acc1;
#pragma unroll
  for (int r = 0; r < 16; ++r) { acc0[r] = 0.f; acc1[r] = 0.f; }

  for (int cc = 0; cc < 8; ++cc) {
    __syncthreads();
#pragma unroll
    for (int it = 0; it < 5; ++it) {
      const int v = it * 256 + tid;
      if (v < 1200) {
        const int sp = v >> 2, cip = (v & 3) * 8;
        const int r = sp / 50, xp = sp - r * 50;
        const int gy = y0b + r, gx = xp - 1;
        bf16x8 val;
#pragma unroll
        for (int j = 0; j < 8; ++j) val[j] = (__bf16)0.f;
        if ((unsigned)gy < 48u && (unsigned)gx < 48u)
          val = *(const bf16x8*)&xtb[(size_t)(gy * 48 + gx) * CCH + cc * 32 + cip];
        *(bf16x8*)&Xl[sp * XLP + cip] = val;
      }
    }
    {
      const int co = tid >> 2, cip = (tid & 3) * 8;
      const __bf16* wsrc = wt + (size_t)(co0 + co) * CCH + cc * 32 + cip;
#pragma unroll
      for (int p = 0; p < 9; ++p) {
        bf16x8 wv = *(const bf16x8*)&wsrc[(size_t)p * CCH * CCH];
        *(bf16x8*)&Wl[(p * 64 + co) * XLP + cip] = wv;
      }
    }
    __syncthreads();
#pragma unroll
    for (int p = 0; p < 9; ++p) {
      const int dy = p / 3, dx = p - 3 * (p / 3);
#pragma unroll
      for (int ks = 0; ks < 2; ++ks) {
        bf16x8 a0 = *(bf16x8*)&Wl[(p * 64 + q) * XLP + ks * 16 + 8 * h];
        bf16x8 a1 = *(bf16x8*)&Wl[(p * 64 + 32 + q) * XLP + ks * 16 + 8 * h];
        bf16x8 bf = *(bf16x8*)&Xl[(sb + dy * 50 + dx) * XLP + ks * 16 + 8 * h];
        acc0 = __builtin_amdgcn_mfma_f32_32x32x16_bf16(a0, bf, acc0, 0, 0, 0);
        acc1 = __builtin_amdgcn_mfma_f32_32x32x16_bf16(a1, bf, acc1, 0, 0, 0);
      }
    }
  }

  __bf16* op = xq + ((size_t)b * NSP + nabs) * CCH + co0;
#pragma unroll
  for (int gg = 0; gg < 4; ++gg) {
    const int cl0 = 8 * gg + 4 * h;
    float v0 = fmaxf(fmaf(acc0[4*gg+0], bn[cl0+0][0], bn[cl0+0][1]), 0.f);
    float v1 = fmaxf(fmaf(acc0[4*gg+1], bn[cl0+1][0], bn[cl0+1][1]), 0.f);
    float v2 = fmaxf(fmaf(acc0[4*gg+2], bn[cl0+2][0], bn[cl0+2][1]), 0.f);
    float v3 = fmaxf(fmaf(acc0[4*gg+3], bn[cl0+3][0], bn[cl0+3][1]), 0.f);
    u32x2 pk; pk[0] = cvtpk(v0, v1); pk[1] = cvtpk(v2, v3);
    *(u32x2*)&op[cl0] = pk;
    float w0 = fmaxf(fmaf(acc1[4*gg+0], bn[32+cl0+0][0], bn[32+cl0+0][1]), 0.f);
    float w1 = fmaxf(fmaf(acc1[4*gg+1], bn[32+cl0+1][0], bn[32+cl0+1][1]), 0.f);
    float w2 = fmaxf(fmaf(acc1[4*gg+2], bn[32+cl0+2][0], bn[32+cl0+2][1]), 0.f);
    float w3 = fmaxf(fmaf(acc1[4*gg+3], bn[32+cl0+3][0], bn[32+cl0+3][1]), 0.f);
    u32x2 qk; qk[0] = cvtpk(w0, w1); qk[1] = cvtpk(w2, w3);
    *(u32x2*)&op[32 + cl0] = qk;
  }
}

// ============ K2: MFMA GEMM, QKV only (64o x 128n tile, 4 waves) ===========
// Y = qkv bf16 [(b*8+head)*3+comp][n][32], +bias; Q pre-scaled by log2e/sqrt(d)
__global__ __launch_bounds__(256) void k_gemm_mfma(const __bf16* __restrict__ X,
    const float* __restrict__ Wm, const float* __restrict__ bias,
    __bf16* __restrict__ Y)
{
  __shared__ __bf16 Xl[128 * XLP];
  __shared__ __bf16 Wl[64 * XLP];
  const int tid = threadIdx.x;
  int bid = blockIdx.x;
  const int nt = bid % 18; bid /= 18;
  const int ot = bid % 12; const int b = bid / 12;
  const int o0 = ot * 64, n0 = nt * 128;
  const int w = tid >> 6, l = tid & 63, h = l >> 5, q = l & 31;

  const int xrow = tid >> 1, xcip = (tid & 1) * 16;
  const int wrow = tid >> 2, wcip = (tid & 3) * 8;
  const __bf16* Xb = X + (size_t)b * NSP * CCH + (size_t)(n0 + xrow) * CCH;

  f32x16 acc0, acc1;
#pragma unroll
  for (int r = 0; r < 16; ++r) { acc0[r] = 0.f; acc1[r] = 0.f; }

  bf16x8 xa0, xa1; float4 wa0, wa1;
  xa0 = *(const bf16x8*)&Xb[xcip];
  xa1 = *(const bf16x8*)&Xb[xcip + 8];
  wa0 = *(const float4*)&Wm[(size_t)(o0 + wrow) * CCH + wcip];
  wa1 = *(const float4*)&Wm[(size_t)(o0 + wrow) * CCH + wcip + 4];

  for (int cc = 0; cc < 8; ++cc) {
    __syncthreads();
    *(bf16x8*)&Xl[xrow * XLP + xcip]     = xa0;
    *(bf16x8*)&Xl[xrow * XLP + xcip + 8] = xa1;
    {
      bf16x8 wv;
      wv[0]=(__bf16)wa0.x; wv[1]=(__bf16)wa0.y; wv[2]=(__bf16)wa0.z; wv[3]=(__bf16)wa0.w;
      wv[4]=(__bf16)wa1.x; wv[5]=(__bf16)wa1.y; wv[6]=(__bf16)wa1.z; wv[7]=(__bf16)wa1.w;
      *(bf16x8*)&Wl[wrow * XLP + wcip] = wv;
    }
    __syncthreads();
    if (cc < 7) {
      const int c1 = (cc + 1) * 32;
      xa0 = *(const bf16x8*)&Xb[c1 + xcip];
      xa1 = *(const bf16x8*)&Xb[c1 + xcip + 8];
      wa0 = *(const float4*)&Wm[(size_t)(o0 + wrow) * CCH + c1 + wcip];
      wa1 = *(const float4*)&Wm[(size_t)(o0 + wrow) * CCH + c1 + wcip + 4];
    }
#pragma unroll
    for (int ks = 0; ks < 2; ++ks) {
      bf16x8 a0 = *(bf16x8*)&Wl[q * XLP + ks * 16 + 8 * h];
      bf16x8 a1 = *(bf16x8*)&Wl[(32 + q) * XLP + ks * 16 + 8 * h];
      bf16x8 bfr = *(bf16x8*)&Xl[(w * 32 + q) * XLP + ks * 16 + 8 * h];
      acc0 = __builtin_amdgcn_mfma_f32_32x32x16_bf16(a0, bfr, acc0, 0, 0, 0);
      acc1 = __builtin_amdgcn_mfma_f32_32x32x16_bf16(a1, bfr, acc1, 0, 0, 0);
    }
  }

  const int n = n0 + w * 32 + q;
  const float QS = 1.4426950408889634f * 0.17677669529663687f;
#pragma unroll
  for (int j = 0; j < 2; ++j) {
    const int t = 2 * ot + j;
    const int head = t / 3, comp = t - 3 * (t / 3);
    const float sc = (comp == 0) ? QS : 1.0f;
    __bf16* yb = Y + (((size_t)(b * NHEAD + head) * 3 + comp) * NSP + n) * DH;
    const f32x16& A = j ? acc1 : acc0;
#pragma unroll
    for (int gg = 0; gg < 4; ++gg) {
      const int e0 = 8 * gg + 4 * h;
      const int ob = o0 + 32 * j + e0;
      u32x2 pk;
      pk[0] = cvtpk((A[4*gg+0] + bias[ob+0]) * sc, (A[4*gg+1] + bias[ob+1]) * sc);
      pk[1] = cvtpk((A[4*gg+2] + bias[ob+2]) * sc, (A[4*gg+3] + bias[ob+3]) * sc);
      *(u32x2*)&yb[e0] = pk;
    }
  }
}

// ============ K3: MFMA flash attention, K-split x4, double-buffered LDS ====
// 2304 blocks: (bh, qb, ks). Each block: 576 keys (9 steps), writes
// UNNORMALIZED partial (bf16) + rowsum (fp32 via ones-MFMA). One barrier/step.
#define KLS 40
#define VLS 72
#define NSPLIT 4
#define NST 9

__global__ __launch_bounds__(256) void k_attn_mfma(const __bf16* __restrict__ qkvt,
    __bf16* __restrict__ parts, float* __restrict__ rss)
{
  __shared__ __bf16 K_lds[2][64 * KLS];
  __shared__ __bf16 Vt_lds[2][32 * VLS];
  const int tid = threadIdx.x;
  const int bid0 = blockIdx.x;
  // XCD swizzle over 2304 = 8 * 288; all 72 blocks of one bh share an XCD
  const int bid = (bid0 & 7) * 288 + (bid0 >> 3);
  const int bh  = bid / 72;
  const int rem = bid % 72;
  const int qb  = rem >> 2;
  const int ks  = rem & 3;
  const int w  = tid >> 6;
  const int l  = tid & 63;
  const int h  = l >> 5;
  const int q  = l & 31;

  const __bf16* qg = qkvt + ((size_t)bh * 3    ) * NSP * DH;
  const __bf16* kg = qkvt + ((size_t)bh * 3 + 1) * NSP * DH;
  const __bf16* vg = qkvt + ((size_t)bh * 3 + 2) * NSP * DH;

  const int nq = qb * 128 + w * 32 + q;
  bf16x8 qf0 = *(const bf16x8*)&qg[(size_t)nq * DH + 8 * h];
  bf16x8 qf1 = *(const bf16x8*)&qg[(size_t)nq * DH + 16 + 8 * h];

  f32x16 zf;
#pragma unroll
  for (int r = 0; r < 16; ++r) zf[r] = 0.f;
  bf16x8 onesA;
#pragma unroll
  for (int j = 0; j < 8; ++j) onesA[j] = (__bf16)1.0f;

  f32x16 acc0, acc1, rsacc;
#pragma unroll
  for (int r = 0; r < 16; ++r) { acc0[r] = 0.f; acc1[r] = 0.f; rsacc[r] = 0.f; }

  const int krow = tid >> 2, kcol = (tid & 3) * 8;
  const int vrow = tid & 63, vcol = (tid >> 6) * 8;
  const int m0 = ks * (NST * 64);

  // ---- prologue: stage step 0 into buf0; preload step-1 regs
  bf16x8 ka = *(const bf16x8*)&kg[(size_t)(m0 + krow) * DH + kcol];
  bf16x8 va = *(const bf16x8*)&vg[(size_t)(m0 + vrow) * DH + vcol];
  *(bf16x8*)&K_lds[0][krow * KLS + kcol] = ka;
#pragma unroll
  for (int j = 0; j < 8; ++j) Vt_lds[0][(vcol + j) * VLS + vrow] = va[j];
  ka = *(const bf16x8*)&kg[(size_t)(m0 + 64 + krow) * DH + kcol];
  va = *(const bf16x8*)&vg[(size_t)(m0 + 64 + vrow) * DH + vcol];
  __syncthreads();

  for (int s = 0; s < NST; ++s) {
    const int cur = s & 1;
    // ---- stage buf^1 for step s+1 (regs loaded during step s-1)
    if (s + 1 < NST) {
      *(bf16x8*)&K_lds[cur ^ 1][krow * KLS + kcol] = ka;
#pragma unroll
      for (int j = 0; j < 8; ++j) Vt_lds[cur ^ 1][(vcol + j) * VLS + vrow] = va[j];
      if (s + 2 < NST) {
        const int m2 = m0 + (s + 2) * 64;
        ka = *(const bf16x8*)&kg[(size_t)(m2 + krow) * DH + kcol];
        va = *(const bf16x8*)&vg[(size_t)(m2 + vrow) * DH + vcol];
      }
    }
    // ---- compute on buf[cur]
    __builtin_amdgcn_s_setprio(1);
#pragma unroll
    for (int kt = 0; kt < 2; ++kt) {
      bf16x8 kfr0 = *(bf16x8*)&K_lds[cur][(32*kt + q) * KLS + 8*h];
      bf16x8 kfr1 = *(bf16x8*)&K_lds[cur][(32*kt + q) * KLS + 16 + 8*h];
      f32x16 sv;
      sv = __builtin_amdgcn_mfma_f32_32x32x16_bf16(kfr0, qf0, zf, 0, 0, 0);
      sv = __builtin_amdgcn_mfma_f32_32x32x16_bf16(kfr1, qf1, sv, 0, 0, 0);
      float p[16];
#pragma unroll
      for (int r = 0; r < 16; ++r) p[r] = fexp2(sv[r]);
#pragma unroll
      for (int m = 0; m < 2; ++m) {
        unsigned pk00 = cvtpk(p[8*m+0], p[8*m+1]);
        unsigned pk01 = cvtpk(p[8*m+2], p[8*m+3]);
        unsigned pk10 = cvtpk(p[8*m+4], p[8*m+5]);
        unsigned pk11 = cvtpk(p[8*m+6], p[8*m+7]);
        asm("v_permlane32_swap_b32 %0, %1" : "+v"(pk00), "+v"(pk10));
        asm("v_permlane32_swap_b32 %0, %1" : "+v"(pk01), "+v"(pk11));
        u32x4 pw = {pk00, pk01, pk10, pk11};
        bf16x8 pfr = __builtin_bit_cast(bf16x8, pw);
        const int MT = 2*kt + m;
        bf16x8 vfr = *(bf16x8*)&Vt_lds[cur][q * VLS + 16*MT + 8*h];
        if (MT & 1) acc1 = __builtin_amdgcn_mfma_f32_32x32x16_bf16(vfr, pfr, acc1, 0, 0, 0);
        else        acc0 = __builtin_amdgcn_mfma_f32_32x32x16_bf16(vfr, pfr, acc0, 0, 0, 0);
        rsacc = __builtin_amdgcn_mfma_f32_32x32x16_bf16(onesA, pfr, rsacc, 0, 0, 0);
      }
    }
    __builtin_amdgcn_s_setprio(0);
    __syncthreads();
  }

  // ---- epilogue: UNNORMALIZED partial + rowsum (normalization fused in proj)
  const int b = bh >> 3, head = bh & 7;
  __bf16* ob = parts + (size_t)ks * 2359296
             + ((size_t)b * NSP + nq) * CCH + head * DH;
#pragma unroll
  for (int gg = 0; gg < 4; ++gg) {
    const int e0 = 8 * gg + 4 * h;
    u32x2 pk;
    pk[0] = cvtpk(acc0[4*gg+0] + acc1[4*gg+0], acc0[4*gg+1] + acc1[4*gg+1]);
    pk[1] = cvtpk(acc0[4*gg+2] + acc1[4*gg+2], acc0[4*gg+3] + acc1[4*gg+3]);
    *(u32x2*)&ob[e0] = pk;
  }
  if (h == 0)
    rss[(size_t)ks * 73728 + (size_t)bh * NSP + nq] = rsacc[0];
}

// ============ K4: proj GEMM with fused split-combine =======================
// X-stage sums the 4 unnormalized partials, scales by 1/rowsum (head == chunk
// index cc), converts to bf16 in LDS. Output fp32 [b][o][n] + bias.
__global__ __launch_bounds__(256) void k_proj_mfma(const __bf16* __restrict__ parts,
    const float* __restrict__ rss, const float* __restrict__ Wm,
    const float* __restrict__ bias, float* __restrict__ Y)
{
  __shared__ __bf16 Xl[128 * XLP];
  __shared__ __bf16 Wl[64 * XLP];
  const int tid = threadIdx.x;
  int bid = blockIdx.x;
  const int nt = bid % 18; bid /= 18;
  const int ot = bid % 4; const int b = bid / 4;
  const int o0 = ot * 64, n0 = nt * 128;
  const int w = tid >> 6, l = tid & 63, h = l >> 5, q = l & 31;

  const int xrow = tid >> 1, xcip = (tid & 1) * 16;
  const int wrow = tid >> 2, wcip = (tid & 3) * 8;
  const int nrow = n0 + xrow;
  const size_t xbase = ((size_t)b * NSP + nrow) * CCH + xcip;
  const size_t rbase = (size_t)(b * NHEAD) * NSP + nrow;

  f32x16 acc0, acc1;
#pragma unroll
  for (int r = 0; r < 16; ++r) { acc0[r] = 0.f; acc1[r] = 0.f; }

  bf16x8 pa[4], pb[4]; float rs4[4]; float4 wa0, wa1;
#pragma unroll
  for (int ksp = 0; ksp < 4; ++ksp) {
    pa[ksp] = *(const bf16x8*)&parts[(size_t)ksp * 2359296 + xbase];
    pb[ksp] = *(const bf16x8*)&parts[(size_t)ksp * 2359296 + xbase + 8];
    rs4[ksp] = rss[(size_t)ksp * 73728 + rbase];
  }
  wa0 = *(const float4*)&Wm[(size_t)(o0 + wrow) * CCH + wcip];
  wa1 = *(const float4*)&Wm[(size_t)(o0 + wrow) * CCH + wcip + 4];

  for (int cc = 0; cc < 8; ++cc) {
    __syncthreads();
    {
      const float rn = frcp(rs4[0] + rs4[1] + rs4[2] + rs4[3]);
      float s0[8], s1[8];
#pragma unroll
      for (int j = 0; j < 8; ++j) {
        s0[j] = ((float)pa[0][j] + (float)pa[1][j] + (float)pa[2][j] + (float)pa[3][j]) * rn;
        s1[j] = ((float)pb[0][j] + (float)pb[1][j] + (float)pb[2][j] + (float)pb[3][j]) * rn;
      }
      u32x4 o0v, o1v;
#pragma unroll
      for (int j = 0; j < 4; ++j) {
        o0v[j] = cvtpk(s0[2*j], s0[2*j+1]);
        o1v[j] = cvtpk(s1[2*j], s1[2*j+1]);
      }
      *(u32x4*)&Xl[xrow * XLP + xcip]     = o0v;
      *(u32x4*)&Xl[xrow * XLP + xcip + 8] = o1v;
      bf16x8 wv;
      wv[0]=(__bf16)wa0.x; wv[1]=(__bf16)wa0.y; wv[2]=(__bf16)wa0.z; wv[3]=(__bf16)wa0.w;
      wv[4]=(__bf16)wa1.x; wv[5]=(__bf16)wa1.y; wv[6]=(__bf16)wa1.z; wv[7]=(__bf16)wa1.w;
      *(bf16x8*)&Wl[wrow * XLP + wcip] = wv;
    }
    __syncthreads();
    if (cc < 7) {
      const int c1 = (cc + 1) * 32;
#pragma unroll
      for (int ksp = 0; ksp < 4; ++ksp) {
        pa[ksp] = *(const bf16x8*)&parts[(size_t)ksp * 2359296 + xbase + c1];
        pb[ksp] = *(const bf16x8*)&parts[(size_t)ksp * 2359296 + xbase + c1 + 8];
        rs4[ksp] = rss[(size_t)ksp * 73728 + (size_t)(cc + 1) * NSP + rbase];
      }
      wa0 = *(const float4*)&Wm[(size_t)(o0 + wrow) * CCH + c1 + wcip];
      wa1 = *(const float4*)&Wm[(size_t)(o0 + wrow) * CCH + c1 + wcip + 4];
    }
#pragma unroll
    for (int ks = 0; ks < 2; ++ks) {
      bf16x8 a0 = *(bf16x8*)&Wl[q * XLP + ks * 16 + 8 * h];
      bf16x8 a1 = *(bf16x8*)&Wl[(32 + q) * XLP + ks * 16 + 8 * h];
      bf16x8 bfr = *(bf16x8*)&Xl[(w * 32 + q) * XLP + ks * 16 + 8 * h];
      acc0 = __builtin_amdgcn_mfma_f32_32x32x16_bf16(a0, bfr, acc0, 0, 0, 0);
      acc1 = __builtin_amdgcn_mfma_f32_32x32x16_bf16(a1, bfr, acc1, 0, 0, 0);
    }
  }

  const int n = n0 + w * 32 + q;
#pragma unroll
  for (int j = 0; j < 2; ++j) {
    const f32x16& A = j ? acc1 : acc0;
#pragma unroll
    for (int r = 0; r < 16; ++r) {
      const int e = (r & 3) + 8 * (r >> 2) + 4 * h;
      const int o = o0 + 32 * j + e;
      Y[((size_t)b * CCH + o) * NSP + n] = A[r] + bias[o];
    }
  }
}

// ---------------------------------------------------------------------------
extern "C" void kernel_launch(void* const* d_in, const int* in_sizes, int n_in,
                              void* d_out, int out_size, void* d_ws, size_t ws_size,
                              hipStream_t stream)
{
  const float* Vx = (const float*)d_in[0];
  const float* cw = (const float*)d_in[1];
  const float* cb = (const float*)d_in[2];
  const float* g  = (const float*)d_in[3];
  const float* be = (const float*)d_in[4];
  const float* mu = (const float*)d_in[5];
  const float* va = (const float*)d_in[6];
  const float* qw = (const float*)d_in[7];
  const float* qb = (const float*)d_in[8];
  const float* pw = (const float*)d_in[9];
  const float* pb = (const float*)d_in[10];
  float* out = (float*)d_out;

  // ws: xq 4.5M | qkv 13.5M | parts 4x4.5M | rss 4x288K   (~37.1 MiB; ws>=76MB)
  __bf16* xq    = (__bf16*)d_ws;
  __bf16* qkvt  = (__bf16*)((char*)d_ws + 4718592);
  __bf16* parts = (__bf16*)((char*)d_ws + 18874368);
  float*  rss   = (float*) ((char*)d_ws + 37748736);

  // d_out doubles as scratch for conv operand pre-transposes
  __bf16* xt = (__bf16*)d_out;                       // 4.5 MiB
  __bf16* wt = (__bf16*)((char*)d_out + 4718592);    // 1.1 MiB

  k_xt<<<1152, 256, 0, stream>>>(Vx, xt);
  k_wt<<<256, 256, 0, stream>>>(cw, wt);
  k_conv_mfma<<<288, 256, 0, stream>>>(xt, wt, cb, g, be, mu, va, xq);
  k_gemm_mfma<<<4*12*18, 256, 0, stream>>>(xq, qw, qb, qkvt);
  k_attn_mfma<<<2304, 256, 0, stream>>>(qkvt, parts, rss);
  k_proj_mfma<<<4*4*18, 256, 0, stream>>>(parts, rss, pw, pb, out);
}